// Round 3
// baseline (225.318 us; speedup 1.0000x reference)
//
#include <hip/hip_runtime.h>

// Problem constants: B=8, L=1024, H=512, F=4
// out = gate * [x | alpha @ x],  gate = sigmoid([x|enc] @ W_gate)
// alpha = masked_softmax(max_f(Y_f Y_f^T)),  Y = relu(x @ W_proj)
//
// Round 15: proj + gate rebuilt as 4-deep-pipelined GEMMs (T3+T4+T5):
// BK=32, 4 LDS buffers, counted s_waitcnt vmcnt(N) (never 0 in-loop) + raw
// s_barrier. Iteration u: wait own tile-u loads (vmcnt) + lgkmcnt(0),
// barrier, DMA tile u+3 into tile u-1's dead slot, compute tile u. Loads
// stay ~3 iterations (~1500 cy) in flight -> latency hidden; the 2-phase
// per-step full drain (m233: ~72% overhead) is gone. 256-wide tiles,
// 512 thr, 1 block/CU, grid=256. New pair-packed BK=32 LDS layout keeps
// ds_read_b128 frags 2-way bank-aliased (free).

typedef _Float16 half8 __attribute__((ext_vector_type(8)));
typedef float floatx4 __attribute__((ext_vector_type(4)));

typedef const __attribute__((address_space(1))) void* gas_ptr;
typedef __attribute__((address_space(3))) void* las_ptr;

#define WAITV(n) asm volatile("s_waitcnt vmcnt(" #n ") lgkmcnt(0)" ::: "memory")

// ---- BK=64 staging machinery (score/attn, unchanged) ----
// Chunk c covers row=c>>3, group kg=c&7, global col (kg^(row&7))*8; LDS dst =
// c*16 B. Row stride 128 B -> rows never alias banks; XOR keeps frags clean.

template<int NCH, int NT>
__device__ __forceinline__ void init_ptrs(const _Float16* src, int row0, int ld,
                                          const _Float16* gp[NCH]) {
  int t = threadIdx.x;
#pragma unroll
  for (int p = 0; p < NCH; ++p) {
    int c = p * NT + t;
    int row = c >> 3;
    int kg = c & 7;
    int gk = (kg ^ (row & 7)) << 3;
    gp[p] = src + (size_t)(row0 + row) * ld + gk;
  }
}

// ---- BK=32 pair-packed staging (proj/gate) ----
// LDS layout: pair p2 = row>>1 owns a 128B line of 8 16B slots; slot s holds
// global (row = 2*p2 + (q>>2), col = (q&3)*8) with q = s ^ (p2&7).
// frag_ld32(row, kg): slot = (kg | ((row&1)<<2)) ^ ((row>>1)&7); 16 lanes of a
// frag hit each 16B bank-window exactly twice -> 2-way alias = free (m136).

template<int NCH, int NT>
__device__ __forceinline__ void init_ptrs32(const _Float16* src, int row0, int ld,
                                            const _Float16* gp[NCH]) {
  int t = threadIdx.x;
#pragma unroll
  for (int p = 0; p < NCH; ++p) {
    int c = p * NT + t;
    int pair = c >> 3, s = c & 7;
    int q = s ^ (pair & 7);
    int row = row0 + pair * 2 + (q >> 2);
    int gk = (q & 3) << 3;
    gp[p] = src + (size_t)row * ld + gk;
  }
}

template<int NCH, int NT>
__device__ __forceinline__ void stage(const _Float16* const gp[NCH], _Float16* ldsbuf) {
  int t = threadIdx.x;
#pragma unroll
  for (int p = 0; p < NCH; ++p)
    __builtin_amdgcn_global_load_lds((gas_ptr)gp[p],
                                     (las_ptr)(ldsbuf + t * 8 + p * NT * 8), 16, 0, 0);
}

template<int NCH>
__device__ __forceinline__ void bump(const _Float16* gp[NCH], int d) {
#pragma unroll
  for (int p = 0; p < NCH; ++p) gp[p] += d;
}

__device__ __forceinline__ half8 frag_ld(const _Float16* lds, int row, int g) {
  return *(const half8*)(lds + row * 64 + ((g ^ (row & 7)) << 3));
}

__device__ __forceinline__ half8 frag_ld32(const _Float16* lds, int row, int kg) {
  int pair = row >> 1;
  int slot = (kg | ((row & 1) << 2)) ^ (pair & 7);
  return *(const half8*)(lds + pair * 64 + slot * 8);
}

// one BK=32 K-step, wave C 128x64 (proj)
__device__ __forceinline__ void kstep84(const _Float16* la, const _Float16* lb,
                                        floatx4 (&acc)[8][4], int ra, int rb, int quad) {
  half8 af[8], bf[4];
#pragma unroll
  for (int mi = 0; mi < 8; ++mi) af[mi] = frag_ld32(la, ra + mi * 16, quad);
#pragma unroll
  for (int ni = 0; ni < 4; ++ni) bf[ni] = frag_ld32(lb, rb + ni * 16, quad);
  __builtin_amdgcn_s_setprio(1);
#pragma unroll
  for (int mi = 0; mi < 8; ++mi)
#pragma unroll
    for (int ni = 0; ni < 4; ++ni)
      acc[mi][ni] = __builtin_amdgcn_mfma_f32_16x16x32_f16(af[mi], bf[ni], acc[mi][ni], 0, 0, 0);
  __builtin_amdgcn_s_setprio(0);
}

// one BK=32 K-step, wave C 64x64 (gate)
__device__ __forceinline__ void kstep44(const _Float16* la, const _Float16* lb,
                                        floatx4 (&acc)[4][4], int ra, int rb, int quad) {
  half8 af[4], bf[4];
#pragma unroll
  for (int mi = 0; mi < 4; ++mi) af[mi] = frag_ld32(la, ra + mi * 16, quad);
#pragma unroll
  for (int ni = 0; ni < 4; ++ni) bf[ni] = frag_ld32(lb, rb + ni * 16, quad);
  __builtin_amdgcn_s_setprio(1);
#pragma unroll
  for (int mi = 0; mi < 4; ++mi)
#pragma unroll
    for (int ni = 0; ni < 4; ++ni)
      acc[mi][ni] = __builtin_amdgcn_mfma_f32_16x16x32_f16(af[mi], bf[ni], acc[mi][ni], 0, 0, 0);
  __builtin_amdgcn_s_setprio(0);
}

// wave tile 64x32, per-lane acc 4x2 (score/attn, unchanged)
__device__ __forceinline__ void mfma_tile42(const _Float16* la, const _Float16* lb,
                                            floatx4 acc[4][2], int wm, int wn,
                                            int l16, int quad) {
#pragma unroll
  for (int kf = 0; kf < 2; ++kf) {
    half8 af[4], bf[2];
#pragma unroll
    for (int i = 0; i < 4; ++i) af[i] = frag_ld(la, wm * 64 + i * 16 + l16, kf * 4 + quad);
#pragma unroll
    for (int i = 0; i < 2; ++i) bf[i] = frag_ld(lb, wn * 32 + i * 16 + l16, kf * 4 + quad);
#pragma unroll
    for (int mi = 0; mi < 4; ++mi)
#pragma unroll
      for (int ni = 0; ni < 2; ++ni)
        acc[mi][ni] = __builtin_amdgcn_mfma_f32_16x16x32_f16(af[mi], bf[ni], acc[mi][ni], 0, 0, 0);
  }
}

#define ZERO_ACC42(acc)                                 \
  _Pragma("unroll") for (int mi = 0; mi < 4; ++mi)      \
  _Pragma("unroll") for (int ni = 0; ni < 2; ++ni)      \
  _Pragma("unroll") for (int r = 0; r < 4; ++r) acc[mi][ni][r] = 0.0f;

// ---- pre-pass ----

__global__ void x_prep_kernel(const float* __restrict__ in, _Float16* __restrict__ x16,
                              _Float16* __restrict__ xT) {
  __shared__ float tile[32][33];
  const int R = 1024, C = 512;
  int c0 = blockIdx.y * 32, r0 = blockIdx.z * 32;
  size_t boff = (size_t)blockIdx.x * R * C;
  in += boff; x16 += boff; xT += boff;
  int tx = threadIdx.x & 31, ty = threadIdx.x >> 5;  // 32 x 8
#pragma unroll
  for (int i = 0; i < 32; i += 8) {
    float v = in[(size_t)(r0 + ty + i) * C + c0 + tx];
    tile[ty + i][tx] = v;
    x16[(size_t)(r0 + ty + i) * C + c0 + tx] = (_Float16)v;
  }
  __syncthreads();
#pragma unroll
  for (int i = 0; i < 32; i += 8)
    xT[(size_t)(c0 + ty + i) * R + r0 + tx] = (_Float16)tile[tx][ty + i];
}

// z=0: Wp (512,2048) -> WpT' (2048,512) row-permuted (col k=h*4+f -> row f*512+h)
// z=1: Wg (1024,1024) -> WgT (1024,1024) plain transpose.
__global__ void w_prep_kernel(const float* __restrict__ Wp, _Float16* __restrict__ WpT,
                              const float* __restrict__ Wg, _Float16* __restrict__ WgT) {
  __shared__ float tile[32][33];
  const float* in; _Float16* out; int R, C, c0, r0;
  if (blockIdx.z == 0) {
    in = Wp; out = WpT; R = 512; C = 2048;
    c0 = blockIdx.x * 32; r0 = blockIdx.y * 32;
  } else {
    in = Wg; out = WgT; R = 1024; C = 1024;
    c0 = (blockIdx.x & 31) * 32; r0 = (blockIdx.y * 2 + (blockIdx.x >> 5)) * 32;
  }
  int tx = threadIdx.x & 31, ty = threadIdx.x >> 5;
#pragma unroll
  for (int i = 0; i < 32; i += 8)
    tile[ty + i][tx] = in[(size_t)(r0 + ty + i) * C + c0 + tx];
  __syncthreads();
#pragma unroll
  for (int i = 0; i < 32; i += 8) {
    int rr = c0 + ty + i;            // original column index of `in`
    int prow = (blockIdx.z == 0) ? ((rr & 3) * 512 + (rr >> 2)) : rr;
    out[(size_t)prow * R + r0 + tx] = (_Float16)tile[tx][ty + i];
  }
}

// ---- K1: y = relu(x @ W_proj + b_proj) -> y_t (B,F,L,H) fp16 ----
// 256 blocks x 512 thr, 256x256 tile, K=512 = 16 BK=32 tiles, 4-deep pipeline.
// Waves 2x4, wave C 128x64. LDS 128 KB -> 1 block/CU.

__global__ __launch_bounds__(512, 2) void proj_kernel(const _Float16* __restrict__ x16,
                                                      const _Float16* __restrict__ WpT,
                                                      const float* __restrict__ bp,
                                                      _Float16* __restrict__ y_t) {
  __shared__ __align__(16) _Float16 ldsA[4][256 * 32];   // 64 KB
  __shared__ __align__(16) _Float16 ldsB[4][256 * 32];   // 64 KB
  int id = blockIdx.x;
  int i0 = (id >> 3) * 256;     // 32 i-tiles
  int n0 = (id & 7) * 256;      // 8 n-tiles
  int t = threadIdx.x, lane = t & 63, w = t >> 6;
  int wm = w >> 2, wn = w & 3;             // 2x4 waves
  int quad = lane >> 4, l16 = lane & 15;
  int ra = wm * 128 + l16, rb = wn * 64 + l16;
  const _Float16* gpA[2]; const _Float16* gpB[2];
  init_ptrs32<2, 512>(x16, i0, 512, gpA);
  init_ptrs32<2, 512>(WpT, n0, 512, gpB);
  floatx4 acc[8][4];
#pragma unroll
  for (int mi = 0; mi < 8; ++mi)
#pragma unroll
    for (int ni = 0; ni < 4; ++ni)
#pragma unroll
      for (int r = 0; r < 4; ++r) acc[mi][ni][r] = 0.0f;
  // prologue: tiles 0,1,2 in flight
  stage<2, 512>(gpA, ldsA[0]); bump<2>(gpA, 32);
  stage<2, 512>(gpB, ldsB[0]); bump<2>(gpB, 32);
  stage<2, 512>(gpA, ldsA[1]); bump<2>(gpA, 32);
  stage<2, 512>(gpB, ldsB[1]); bump<2>(gpB, 32);
  stage<2, 512>(gpA, ldsA[2]); bump<2>(gpA, 32);
  stage<2, 512>(gpB, ldsB[2]); bump<2>(gpB, 32);
#pragma unroll 1
  for (int u = 0; u < 13; ++u) {
    WAITV(8);                               // own tile-u loads retired
    __builtin_amdgcn_s_barrier();           // -> all waves' tile-u staged; slot u-1 dead
    stage<2, 512>(gpA, ldsA[(u + 3) & 3]); bump<2>(gpA, 32);
    stage<2, 512>(gpB, ldsB[(u + 3) & 3]); bump<2>(gpB, 32);
    kstep84(ldsA[u & 3], ldsB[u & 3], acc, ra, rb, quad);
  }
  WAITV(8); __builtin_amdgcn_s_barrier(); kstep84(ldsA[1], ldsB[1], acc, ra, rb, quad);
  WAITV(4); __builtin_amdgcn_s_barrier(); kstep84(ldsA[2], ldsB[2], acc, ra, rb, quad);
  WAITV(0); __builtin_amdgcn_s_barrier(); kstep84(ldsA[3], ldsB[3], acc, ra, rb, quad);
#pragma unroll
  for (int mi = 0; mi < 8; ++mi)
#pragma unroll
    for (int ni = 0; ni < 4; ++ni)
#pragma unroll
      for (int r = 0; r < 4; ++r) {
        int gr = i0 + wm * 128 + mi * 16 + quad * 4 + r;  // 0..8191
        int gc = n0 + wn * 64 + ni * 16 + l16;            // permuted col f*512+h
        int f = gc >> 9, h = gc & 511;
        float c = fmaxf(acc[mi][ni][r] + bp[h * 4 + f], 0.0f);
        int b = gr >> 10, l = gr & 1023;
        y_t[(((size_t)(b * 4 + f)) * 1024 + l) * 512 + h] = (_Float16)c;
      }
}

// ---- K2: S[b,i,j] = max_f sum_h Y_f[i,h] Y_f[j,h]; S symmetric ----
// 576 blocks (8 b x 72 upper-tri 128x64 tiles) x 256 thr; b = id & 7 XCD pin.

__global__ __launch_bounds__(256, 3) void score_kernel(const _Float16* __restrict__ y_t,
                                                       float* __restrict__ S) {
  __shared__ __align__(16) char smem[49152];
  _Float16* LA0 = (_Float16*)smem;              // 16 KB (128x64)
  _Float16* LA1 = (_Float16*)(smem + 16384);    // 16 KB
  _Float16* LB0 = (_Float16*)(smem + 32768);    // 8 KB (64x64)
  _Float16* LB1 = (_Float16*)(smem + 40960);    // 8 KB
  int id = blockIdx.x;
  int b = id & 7;
  int tt = id >> 3;            // 0..71 upper-tri half-tile index
  int ti = 0;
  while (tt >= 16 - 2 * ti) { tt -= 16 - 2 * ti; ++ti; }
  int jh = 2 * ti + tt;        // 2*ti .. 15
  int i0 = ti * 128, j0 = jh * 64;
  int t = threadIdx.x, lane = t & 63, w = t >> 6;
  int wm = w >> 1, wn = w & 1, quad = lane >> 4, l16 = lane & 15;
  const int PLANE = 1024 * 512;
  const _Float16* base = y_t + (size_t)b * 4 * PLANE;
  const _Float16* gpA[4]; const _Float16* gpB[2];
  init_ptrs<4, 256>(base, i0, 512, gpA);
  init_ptrs<2, 256>(base, j0, 512, gpB);
  floatx4 acc[4][2], smax[4][2];
  ZERO_ACC42(acc);
  stage<4, 256>(gpA, LA0); bump<4>(gpA, 64);
  stage<2, 256>(gpB, LB0); bump<2>(gpB, 64);
#pragma unroll 1
  for (int f = 0; f < 4; ++f) {
#pragma unroll 1
    for (int kt = 0; kt < 8; ++kt) {
      __syncthreads();
      if (f * 8 + kt < 31) {
        if (kt == 7) { bump<4>(gpA, PLANE - 512); bump<2>(gpB, PLANE - 512); }
        stage<4, 256>(gpA, ((kt + 1) & 1) ? LA1 : LA0); bump<4>(gpA, 64);
        stage<2, 256>(gpB, ((kt + 1) & 1) ? LB1 : LB0); bump<2>(gpB, 64);
      }
      mfma_tile42((kt & 1) ? LA1 : LA0, (kt & 1) ? LB1 : LB0, acc, wm, wn, l16, quad);
    }
    if (f == 0) {
#pragma unroll
      for (int mi = 0; mi < 4; ++mi)
#pragma unroll
        for (int ni = 0; ni < 2; ++ni) smax[mi][ni] = acc[mi][ni];
    } else {
#pragma unroll
      for (int mi = 0; mi < 4; ++mi)
#pragma unroll
        for (int ni = 0; ni < 2; ++ni)
#pragma unroll
          for (int r = 0; r < 4; ++r)
            smax[mi][ni][r] = fmaxf(smax[mi][ni][r], acc[mi][ni][r]);
    }
    ZERO_ACC42(acc);
  }
  float* Sb = S + (size_t)b * 1024 * 1024;
#pragma unroll
  for (int mi = 0; mi < 4; ++mi)
#pragma unroll
    for (int ni = 0; ni < 2; ++ni)
#pragma unroll
      for (int r = 0; r < 4; ++r) {
        int gi = i0 + wm * 64 + mi * 16 + quad * 4 + r;
        int gj = j0 + wn * 32 + ni * 16 + l16;
        Sb[(size_t)gi * 1024 + gj] = smax[mi][ni][r];
      }
  if (jh >= 2 * ti + 2) {
    __syncthreads();                 // staging buffers dead
    float* tl = (float*)smem;        // [128][65] fp32
#pragma unroll
    for (int mi = 0; mi < 4; ++mi)
#pragma unroll
      for (int ni = 0; ni < 2; ++ni)
#pragma unroll
        for (int r = 0; r < 4; ++r)
          tl[(wm * 64 + mi * 16 + quad * 4 + r) * 65 + (wn * 32 + ni * 16 + l16)] =
              smax[mi][ni][r];
    __syncthreads();
#pragma unroll 1
    for (int k = 0; k < 32; ++k) {
      int flat = k * 256 + t;        // 0..8191
      int rm = flat >> 7, cm = flat & 127;
      Sb[(size_t)(j0 + rm) * 1024 + (i0 + cm)] = tl[cm * 65 + rm];
    }
  }
}

// ---- K3: allennlp masked softmax per row -> alpha fp16 ----

__global__ __launch_bounds__(256) void softmax_kernel(const float* __restrict__ S,
                                                      const int* __restrict__ xmask,
                                                      _Float16* __restrict__ alpha) {
  __shared__ float red[16];
  int id = blockIdx.x;
  int b = id & 7, l = id >> 3;        // b XCD pin, l: 0..1023
  int row = b * 1024 + l;
  const float* sr = S + (size_t)row * 1024;
  const int* mr = xmask + b * 1024;
  int t = threadIdx.x, lane = t & 63, wid = t >> 6;
  int rm = mr[l];
  float v[4], mm[4];
  float vmax = 0.0f;
#pragma unroll
  for (int q = 0; q < 4; ++q) {
    int i = t + q * 256;
    int m = (rm && mr[i] && (i != l)) ? 1 : 0;
    mm[q] = (float)m;
    v[q] = m ? sr[i] : 0.0f;
    vmax = fmaxf(vmax, v[q]);
  }
  for (int off = 32; off; off >>= 1) vmax = fmaxf(vmax, __shfl_down(vmax, off));
  if (lane == 0) red[wid] = vmax;
  __syncthreads();
  if (t == 0) red[8] = fmaxf(fmaxf(red[0], red[1]), fmaxf(red[2], red[3]));
  __syncthreads();
  vmax = red[8];
  float e[4], E = 0.0f, E2 = 0.0f;
#pragma unroll
  for (int q = 0; q < 4; ++q) {
    e[q] = expf(v[q] - vmax);
    E += e[q];
    E2 += e[q] * mm[q];
  }
  for (int off = 32; off; off >>= 1) {
    E += __shfl_down(E, off);
    E2 += __shfl_down(E2, off);
  }
  if (lane == 0) { red[wid] = E; red[4 + wid] = E2; }
  __syncthreads();
  if (t == 0) {
    red[9] = red[0] + red[1] + red[2] + red[3];
    red[10] = red[4] + red[5] + red[6] + red[7];
  }
  __syncthreads();
  E = red[9]; E2 = red[10];
  float inv = 1.0f / (E2 + 1e-13f * E);
  _Float16* ar = alpha + (size_t)row * 1024;
#pragma unroll
  for (int q = 0; q < 4; ++q) {
    int i = t + q * 256;
    ar[i] = (_Float16)(e[q] * mm[q] * inv);
  }
}

// ---- K4: enc[b] = alpha[b] @ x[b]  (xT (B,H,L) as B-operand) ----
// 512 blocks x 256 thr: 64-row i-tiles x 4 n-tiles x 8 b; b = id & 7 XCD pin.

__global__ __launch_bounds__(256) void attn_kernel(const _Float16* __restrict__ alpha,
                                                   const _Float16* __restrict__ xT,
                                                   _Float16* __restrict__ enc) {
  __shared__ __align__(16) _Float16 ldsA[2][64 * 64];
  __shared__ __align__(16) _Float16 ldsB[2][128 * 64];
  int id = blockIdx.x;
  int b = id & 7;
  int r2 = id >> 3;                 // 0..63
  int i0 = (r2 >> 2) * 64;
  int n0 = (r2 & 3) * 128;
  const _Float16* A = alpha + (size_t)b * 1024 * 1024;
  const _Float16* Bm = xT + (size_t)b * 512 * 1024;
  int t = threadIdx.x, lane = t & 63, wn = t >> 6;   // wave grid 1x4
  int quad = lane >> 4, l16 = lane & 15;
  const _Float16* gpA[2]; const _Float16* gpB[4];
  init_ptrs<2, 256>(A, i0, 1024, gpA);
  init_ptrs<4, 256>(Bm, n0, 1024, gpB);
  floatx4 acc[4][2];
  ZERO_ACC42(acc);
  stage<2, 256>(gpA, ldsA[0]); bump<2>(gpA, 64);
  stage<4, 256>(gpB, ldsB[0]); bump<4>(gpB, 64);
#pragma unroll 1
  for (int kt = 0; kt < 16; ++kt) {
    __syncthreads();
    if (kt < 15) {
      stage<2, 256>(gpA, ldsA[(kt + 1) & 1]); bump<2>(gpA, 64);
      stage<4, 256>(gpB, ldsB[(kt + 1) & 1]); bump<4>(gpB, 64);
    }
    const _Float16* la = ldsA[kt & 1];
    const _Float16* lb = ldsB[kt & 1];
#pragma unroll
    for (int kf = 0; kf < 2; ++kf) {
      half8 af[4], bf[2];
#pragma unroll
      for (int i = 0; i < 4; ++i) af[i] = frag_ld(la, i * 16 + l16, kf * 4 + quad);
#pragma unroll
      for (int i = 0; i < 2; ++i) bf[i] = frag_ld(lb, wn * 32 + i * 16 + l16, kf * 4 + quad);
#pragma unroll
      for (int mi = 0; mi < 4; ++mi)
#pragma unroll
        for (int ni = 0; ni < 2; ++ni)
          acc[mi][ni] = __builtin_amdgcn_mfma_f32_16x16x32_f16(af[mi], bf[ni], acc[mi][ni], 0, 0, 0);
    }
  }
  _Float16* eb = enc + (size_t)b * 1024 * 512;
#pragma unroll
  for (int mi = 0; mi < 4; ++mi)
#pragma unroll
    for (int ni = 0; ni < 2; ++ni)
#pragma unroll
      for (int r = 0; r < 4; ++r) {
        int gr = i0 + mi * 16 + quad * 4 + r;
        int gc = n0 + wn * 32 + ni * 16 + l16;
        eb[(size_t)gr * 512 + gc] = (_Float16)acc[mi][ni][r];
      }
}

// ---- K5: gate = sigmoid([x|enc] @ W_gate + b_gate); out = gate*[x16|enc] ----
// 256 blocks x 512 thr, 256x128 tile, K=1024 = 32 BK=32 tiles, 4-deep
// pipeline. Waves 4x2, wave C 64x64. A switches x16 -> enc at tile 16.
// LDS 96 KB -> 1 block/CU.

__global__ __launch_bounds__(512, 2) void gate_kernel(const _Float16* __restrict__ x16,
                                                      const _Float16* __restrict__ enc,
                                                      const _Float16* __restrict__ WgT,
                                                      const float* __restrict__ bg,
                                                      float* __restrict__ out) {
  __shared__ __align__(16) _Float16 ldsA[4][256 * 32];   // 64 KB
  __shared__ __align__(16) _Float16 ldsB[4][128 * 32];   // 32 KB
  int id = blockIdx.x;
  int i0 = (id >> 3) * 256;     // 32 i-tiles
  int n0 = (id & 7) * 128;      // 8 n-tiles
  int t = threadIdx.x, lane = t & 63, w = t >> 6;
  int wm = w >> 1, wn = w & 1;             // 4x2 waves
  int quad = lane >> 4, l16 = lane & 15;
  int ra = wm * 64 + l16, rb = wn * 64 + l16;
  const _Float16* gpA[2]; const _Float16* gpA2[2]; const _Float16* gpB[1];
  init_ptrs32<2, 512>(x16, i0, 512, gpA);
  init_ptrs32<2, 512>(enc, i0, 512, gpA2);
  init_ptrs32<1, 512>(WgT, n0, 1024, gpB);
  floatx4 acc[4][4];
#pragma unroll
  for (int mi = 0; mi < 4; ++mi)
#pragma unroll
    for (int ni = 0; ni < 4; ++ni)
#pragma unroll
      for (int r = 0; r < 4; ++r) acc[mi][ni][r] = 0.0f;
  // prologue: tiles 0,1,2
  stage<2, 512>(gpA, ldsA[0]); bump<2>(gpA, 32);
  stage<1, 512>(gpB, ldsB[0]); bump<1>(gpB, 32);
  stage<2, 512>(gpA, ldsA[1]); bump<2>(gpA, 32);
  stage<1, 512>(gpB, ldsB[1]); bump<1>(gpB, 32);
  stage<2, 512>(gpA, ldsA[2]); bump<2>(gpA, 32);
  stage<1, 512>(gpB, ldsB[2]); bump<1>(gpB, 32);
#pragma unroll 1
  for (int u = 0; u < 29; ++u) {
    WAITV(6);
    __builtin_amdgcn_s_barrier();
    int v = u + 3;
    if (v < 16) { stage<2, 512>(gpA, ldsA[v & 3]); bump<2>(gpA, 32); }
    else        { stage<2, 512>(gpA2, ldsA[v & 3]); bump<2>(gpA2, 32); }
    stage<1, 512>(gpB, ldsB[v & 3]); bump<1>(gpB, 32);
    kstep44(ldsA[u & 3], ldsB[u & 3], acc, ra, rb, quad);
  }
  WAITV(6); __builtin_amdgcn_s_barrier(); kstep44(ldsA[1], ldsB[1], acc, ra, rb, quad);
  WAITV(3); __builtin_amdgcn_s_barrier(); kstep44(ldsA[2], ldsB[2], acc, ra, rb, quad);
  WAITV(0); __builtin_amdgcn_s_barrier(); kstep44(ldsA[3], ldsB[3], acc, ra, rb, quad);
#pragma unroll
  for (int mi = 0; mi < 4; ++mi)
#pragma unroll
    for (int ni = 0; ni < 4; ++ni)
#pragma unroll
      for (int r = 0; r < 4; ++r) {
        int gr = i0 + wm * 64 + mi * 16 + quad * 4 + r;  // 0..8191
        int gc = n0 + wn * 64 + ni * 16 + l16;           // 0..1023
        float c = acc[mi][ni][r] + bg[gc];
        float g = 1.0f / (1.0f + expf(-c));
        float jv = (gc < 512) ? (float)x16[(size_t)gr * 512 + gc]
                              : (float)enc[(size_t)gr * 512 + (gc - 512)];
        out[(size_t)gr * 1024 + gc] = g * jv;
      }
}

// ---- launch ----

extern "C" void kernel_launch(void* const* d_in, const int* in_sizes, int n_in,
                              void* d_out, int out_size, void* d_ws, size_t ws_size,
                              hipStream_t stream) {
  const float* x  = (const float*)d_in[0];   // (8,1024,512)
  const int* xm   = (const int*)d_in[1];     // (8,1024)
  const float* Wp = (const float*)d_in[2];   // (512,2048)
  const float* bp = (const float*)d_in[3];   // (2048)
  const float* Wg = (const float*)d_in[4];   // (1024,1024)
  const float* bg = (const float*)d_in[5];   // (1024)
  float* out = (float*)d_out;

  char* ws = (char*)d_ws;
  const size_t MB = 1024 * 1024;
  _Float16* x16 = (_Float16*)(ws);            // 8 MB  (8192,512)
  _Float16* xT  = (_Float16*)(ws + 8 * MB);   // 8 MB  (8,512,1024)
  _Float16* WpT = (_Float16*)(ws + 16 * MB);  // 2 MB  (2048,512) row-permuted
  _Float16* WgT = (_Float16*)(ws + 18 * MB);  // 2 MB  (1024,1024)
  _Float16* y_t = (_Float16*)(ws + 20 * MB);  // 32 MB (8,4,1024,512)
  float*    S   = (float*)(ws + 52 * MB);     // 32 MB (8,1024,1024)  [end: 84 MB]
  // y_t is dead after score_kernel: alias alpha/enc onto it
  _Float16* alpha = (_Float16*)(ws + 20 * MB); // 16 MB (8,1024,1024)
  _Float16* enc   = (_Float16*)(ws + 36 * MB); // 8 MB  (8,1024,512)

  x_prep_kernel<<<dim3(8, 16, 32), 256, 0, stream>>>(x, x16, xT);
  w_prep_kernel<<<dim3(64, 16, 2), 256, 0, stream>>>(Wp, WpT, Wg, WgT);

  proj_kernel<<<256, 512, 0, stream>>>(x16, WpT, bp, y_t);
  score_kernel<<<576, 256, 0, stream>>>(y_t, S);
  softmax_kernel<<<8192, 256, 0, stream>>>(S, xm, alpha);
  attn_kernel<<<512, 256, 0, stream>>>(alpha, xT, enc);
  gate_kernel<<<256, 512, 0, stream>>>(x16, enc, WgT, bg, out);
}

// Round 4
// 213.542 us; speedup vs baseline: 1.0551x; 1.0551x over previous
//
#include <hip/hip_runtime.h>

// Problem constants: B=8, L=1024, H=512, F=4
// out = gate * [x | alpha @ x],  gate = sigmoid([x|enc] @ W_gate)
// alpha = masked_softmax(max_f(Y_f Y_f^T)),  Y = relu(x @ W_proj)
//
// Round 16: fix R15's two measured failures (gate 46us, MfmaUtil 13.5%,
// FETCH 74MB): (1) restore R14 XCD-batch pinning on proj/gate so per-XCD
// working set (~3.5MB) is L2-resident; (2) keep the 4-deep counted-vmcnt
// pipeline but at 128x128/BK=32/256thr/64KB LDS -> 2 blocks/CU, so the
// second resident block covers barrier stalls (m114 overlap) AND loads get
// 3 K-steps (~900+cy) in flight (T4). Also merged x_prep+w_prep into one
// dispatch. score/softmax/attn unchanged from R13/R14.

typedef _Float16 half8 __attribute__((ext_vector_type(8)));
typedef float floatx4 __attribute__((ext_vector_type(4)));

typedef const __attribute__((address_space(1))) void* gas_ptr;
typedef __attribute__((address_space(3))) void* las_ptr;

#define WAITV(n) asm volatile("s_waitcnt vmcnt(" #n ") lgkmcnt(0)" ::: "memory")

// ---- BK=64 staging machinery (score/attn) ----
// Chunk c covers row=c>>3, group kg=c&7, global col (kg^(row&7))*8; LDS dst =
// c*16 B. Row stride 128 B -> rows never alias banks; XOR keeps frags clean.

template<int NCH, int NT>
__device__ __forceinline__ void init_ptrs(const _Float16* src, int row0, int ld,
                                          const _Float16* gp[NCH]) {
  int t = threadIdx.x;
#pragma unroll
  for (int p = 0; p < NCH; ++p) {
    int c = p * NT + t;
    int row = c >> 3;
    int kg = c & 7;
    int gk = (kg ^ (row & 7)) << 3;
    gp[p] = src + (size_t)(row0 + row) * ld + gk;
  }
}

// ---- BK=32 pair-packed staging (proj/gate) ----
// LDS layout: pair p2 = row>>1 owns a 128B line of 8 16B slots; slot s holds
// global (row = 2*p2 + (q>>2), col = (q&3)*8) with q = s ^ (p2&7).
// frag_ld32(row, kg): slot = (kg | ((row&1)<<2)) ^ ((row>>1)&7); 16 lanes of a
// frag hit each 16B window exactly twice -> 2-way alias = free (m136).

template<int NCH, int NT>
__device__ __forceinline__ void init_ptrs32(const _Float16* src, int row0, int ld,
                                            const _Float16* gp[NCH]) {
  int t = threadIdx.x;
#pragma unroll
  for (int p = 0; p < NCH; ++p) {
    int c = p * NT + t;
    int pair = c >> 3, s = c & 7;
    int q = s ^ (pair & 7);
    int row = row0 + pair * 2 + (q >> 2);
    int gk = (q & 3) << 3;
    gp[p] = src + (size_t)row * ld + gk;
  }
}

template<int NCH, int NT>
__device__ __forceinline__ void stage(const _Float16* const gp[NCH], _Float16* ldsbuf) {
  int t = threadIdx.x;
#pragma unroll
  for (int p = 0; p < NCH; ++p)
    __builtin_amdgcn_global_load_lds((gas_ptr)gp[p],
                                     (las_ptr)(ldsbuf + t * 8 + p * NT * 8), 16, 0, 0);
}

template<int NCH>
__device__ __forceinline__ void bump(const _Float16* gp[NCH], int d) {
#pragma unroll
  for (int p = 0; p < NCH; ++p) gp[p] += d;
}

__device__ __forceinline__ half8 frag_ld(const _Float16* lds, int row, int g) {
  return *(const half8*)(lds + row * 64 + ((g ^ (row & 7)) << 3));
}

__device__ __forceinline__ half8 frag_ld32(const _Float16* lds, int row, int kg) {
  int pair = row >> 1;
  int slot = (kg | ((row & 1) << 2)) ^ (pair & 7);
  return *(const half8*)(lds + pair * 64 + slot * 8);
}

// one BK=32 K-step, wave C 64x64 (proj/gate), acc 4x4
__device__ __forceinline__ void kstep44(const _Float16* la, const _Float16* lb,
                                        floatx4 (&acc)[4][4], int ra, int rb, int quad) {
  half8 af[4], bf[4];
#pragma unroll
  for (int mi = 0; mi < 4; ++mi) af[mi] = frag_ld32(la, ra + mi * 16, quad);
#pragma unroll
  for (int ni = 0; ni < 4; ++ni) bf[ni] = frag_ld32(lb, rb + ni * 16, quad);
  __builtin_amdgcn_s_setprio(1);
#pragma unroll
  for (int mi = 0; mi < 4; ++mi)
#pragma unroll
    for (int ni = 0; ni < 4; ++ni)
      acc[mi][ni] = __builtin_amdgcn_mfma_f32_16x16x32_f16(af[mi], bf[ni], acc[mi][ni], 0, 0, 0);
  __builtin_amdgcn_s_setprio(0);
}

// wave tile 64x32, per-lane acc 4x2 (score/attn)
__device__ __forceinline__ void mfma_tile42(const _Float16* la, const _Float16* lb,
                                            floatx4 acc[4][2], int wm, int wn,
                                            int l16, int quad) {
#pragma unroll
  for (int kf = 0; kf < 2; ++kf) {
    half8 af[4], bf[2];
#pragma unroll
    for (int i = 0; i < 4; ++i) af[i] = frag_ld(la, wm * 64 + i * 16 + l16, kf * 4 + quad);
#pragma unroll
    for (int i = 0; i < 2; ++i) bf[i] = frag_ld(lb, wn * 32 + i * 16 + l16, kf * 4 + quad);
#pragma unroll
    for (int mi = 0; mi < 4; ++mi)
#pragma unroll
      for (int ni = 0; ni < 2; ++ni)
        acc[mi][ni] = __builtin_amdgcn_mfma_f32_16x16x32_f16(af[mi], bf[ni], acc[mi][ni], 0, 0, 0);
  }
}

#define ZERO_ACC44(acc)                                 \
  _Pragma("unroll") for (int mi = 0; mi < 4; ++mi)      \
  _Pragma("unroll") for (int ni = 0; ni < 4; ++ni)      \
  _Pragma("unroll") for (int r = 0; r < 4; ++r) acc[mi][ni][r] = 0.0f;

#define ZERO_ACC42(acc)                                 \
  _Pragma("unroll") for (int mi = 0; mi < 4; ++mi)      \
  _Pragma("unroll") for (int ni = 0; ni < 2; ++ni)      \
  _Pragma("unroll") for (int r = 0; r < 4; ++r) acc[mi][ni][r] = 0.0f;

// ---- merged pre-pass: ids [0,4096) = x_prep, [4096,6144) = w_prep ----

__global__ __launch_bounds__(256) void prep_kernel(const float* __restrict__ xin,
                                                   _Float16* __restrict__ x16,
                                                   _Float16* __restrict__ xT,
                                                   const float* __restrict__ Wp,
                                                   _Float16* __restrict__ WpT,
                                                   const float* __restrict__ Wg,
                                                   _Float16* __restrict__ WgT) {
  __shared__ float tile[32][33];
  int id = blockIdx.x;
  int tx = threadIdx.x & 31, ty = threadIdx.x >> 5;  // 32 x 8
  if (id < 4096) {
    // x_prep: b = id&7 (XCD pin), c-tile, r-tile
    const int R = 1024, C = 512;
    int b = id & 7, rest = id >> 3;
    int c0 = (rest & 15) * 32, r0 = (rest >> 4) * 32;
    size_t boff = (size_t)b * R * C;
    const float* in = xin + boff;
    _Float16* o16 = x16 + boff;
    _Float16* oT = xT + boff;
#pragma unroll
    for (int i = 0; i < 32; i += 8) {
      float v = in[(size_t)(r0 + ty + i) * C + c0 + tx];
      tile[ty + i][tx] = v;
      o16[(size_t)(r0 + ty + i) * C + c0 + tx] = (_Float16)v;
    }
    __syncthreads();
#pragma unroll
    for (int i = 0; i < 32; i += 8)
      oT[(size_t)(c0 + ty + i) * R + r0 + tx] = (_Float16)tile[tx][ty + i];
  } else {
    // w_prep. z=0: Wp (512,2048) -> WpT' (2048,512) row-permuted
    //          (orig col k=h*4+f -> row f*512+h). z=1: Wg -> WgT transpose.
    int w = id - 4096;
    int bx = w & 63, by = (w >> 6) & 15, bz = w >> 10;
    const float* in; _Float16* out; int R, C, c0, r0;
    if (bz == 0) {
      in = Wp; out = WpT; R = 512; C = 2048;
      c0 = bx * 32; r0 = by * 32;
    } else {
      in = Wg; out = WgT; R = 1024; C = 1024;
      c0 = (bx & 31) * 32; r0 = (by * 2 + (bx >> 5)) * 32;
    }
#pragma unroll
    for (int i = 0; i < 32; i += 8)
      tile[ty + i][tx] = in[(size_t)(r0 + ty + i) * C + c0 + tx];
    __syncthreads();
#pragma unroll
    for (int i = 0; i < 32; i += 8) {
      int rr = c0 + ty + i;            // original column index of `in`
      int prow = (bz == 0) ? ((rr & 3) * 512 + (rr >> 2)) : rr;
      out[(size_t)prow * R + r0 + tx] = (_Float16)tile[tx][ty + i];
    }
  }
}

// ---- K1: y = relu(x @ W_proj + b_proj) -> y_t (B,F,L,H) fp16 ----
// 1024 blocks x 256 thr, XCD-batch pinned (xcd = id&7 = b). 128x128 tile,
// BK=32, 4-deep counted-vmcnt pipeline, 64KB LDS -> 2 blocks/CU.

__global__ __launch_bounds__(256, 2) void proj_kernel(const _Float16* __restrict__ x16,
                                                      const _Float16* __restrict__ WpT,
                                                      const float* __restrict__ bp,
                                                      _Float16* __restrict__ y_t) {
  __shared__ __align__(16) _Float16 ldsA[4][128 * 32];   // 32 KB
  __shared__ __align__(16) _Float16 ldsB[4][128 * 32];   // 32 KB
  int id = blockIdx.x;
  int xcd = id & 7, r = id >> 3;            // r: 0..127
  int i0 = (xcd * 8 + (r & 7)) * 128;       // i-tile pinned to XCD = batch
  int n0 = (r >> 3) * 128;                  // 0..15
  int t = threadIdx.x, lane = t & 63, w = t >> 6;
  int wm = w >> 1, wn = w & 1, quad = lane >> 4, l16 = lane & 15;
  int ra = wm * 64 + l16, rb = wn * 64 + l16;
  const _Float16* gpA[2]; const _Float16* gpB[2];
  init_ptrs32<2, 256>(x16, i0, 512, gpA);
  init_ptrs32<2, 256>(WpT, n0, 512, gpB);
  floatx4 acc[4][4];
  ZERO_ACC44(acc);
  // prologue: tiles 0,1,2 in flight (4 loads/thread/tile)
  stage<2, 256>(gpA, ldsA[0]); bump<2>(gpA, 32);
  stage<2, 256>(gpB, ldsB[0]); bump<2>(gpB, 32);
  stage<2, 256>(gpA, ldsA[1]); bump<2>(gpA, 32);
  stage<2, 256>(gpB, ldsB[1]); bump<2>(gpB, 32);
  stage<2, 256>(gpA, ldsA[2]); bump<2>(gpA, 32);
  stage<2, 256>(gpB, ldsB[2]); bump<2>(gpB, 32);
#pragma unroll 1
  for (int u = 0; u < 13; ++u) {           // K=512 -> 16 BK=32 tiles
    WAITV(8);                              // own tile-u loads retired
    __builtin_amdgcn_s_barrier();          // all waves staged tile u; slot u-1 dead
    stage<2, 256>(gpA, ldsA[(u + 3) & 3]); bump<2>(gpA, 32);
    stage<2, 256>(gpB, ldsB[(u + 3) & 3]); bump<2>(gpB, 32);
    kstep44(ldsA[u & 3], ldsB[u & 3], acc, ra, rb, quad);
  }
  WAITV(8); __builtin_amdgcn_s_barrier(); kstep44(ldsA[1], ldsB[1], acc, ra, rb, quad);
  WAITV(4); __builtin_amdgcn_s_barrier(); kstep44(ldsA[2], ldsB[2], acc, ra, rb, quad);
  WAITV(0); __builtin_amdgcn_s_barrier(); kstep44(ldsA[3], ldsB[3], acc, ra, rb, quad);
#pragma unroll
  for (int mi = 0; mi < 4; ++mi)
#pragma unroll
    for (int ni = 0; ni < 4; ++ni)
#pragma unroll
      for (int r2 = 0; r2 < 4; ++r2) {
        int gr = i0 + wm * 64 + mi * 16 + quad * 4 + r2;  // 0..8191
        int gc = n0 + wn * 64 + ni * 16 + l16;            // permuted col f*512+h
        int f = gc >> 9, h = gc & 511;
        float c = fmaxf(acc[mi][ni][r2] + bp[h * 4 + f], 0.0f);
        int b = gr >> 10, l = gr & 1023;
        y_t[(((size_t)(b * 4 + f)) * 1024 + l) * 512 + h] = (_Float16)c;
      }
}

// ---- K2: S[b,i,j] = max_f sum_h Y_f[i,h] Y_f[j,h]; S symmetric ----
// 576 blocks (8 b x 72 upper-tri 128x64 tiles) x 256 thr; b = id & 7 XCD pin.
// 48KB LDS -> 3 blocks/CU. Diagonal covered by jh=2ti/2ti+1 direct;
// jh>=2ti+2 mirrored via [128][65] fp32 LDS transpose (conflict-free).

__global__ __launch_bounds__(256, 3) void score_kernel(const _Float16* __restrict__ y_t,
                                                       float* __restrict__ S) {
  __shared__ __align__(16) char smem[49152];
  _Float16* LA0 = (_Float16*)smem;              // 16 KB (128x64)
  _Float16* LA1 = (_Float16*)(smem + 16384);    // 16 KB
  _Float16* LB0 = (_Float16*)(smem + 32768);    // 8 KB (64x64)
  _Float16* LB1 = (_Float16*)(smem + 40960);    // 8 KB
  int id = blockIdx.x;
  int b = id & 7;
  int tt = id >> 3;            // 0..71 upper-tri half-tile index
  int ti = 0;
  while (tt >= 16 - 2 * ti) { tt -= 16 - 2 * ti; ++ti; }
  int jh = 2 * ti + tt;        // 2*ti .. 15
  int i0 = ti * 128, j0 = jh * 64;
  int t = threadIdx.x, lane = t & 63, w = t >> 6;
  int wm = w >> 1, wn = w & 1, quad = lane >> 4, l16 = lane & 15;
  const int PLANE = 1024 * 512;
  const _Float16* base = y_t + (size_t)b * 4 * PLANE;
  const _Float16* gpA[4]; const _Float16* gpB[2];
  init_ptrs<4, 256>(base, i0, 512, gpA);
  init_ptrs<2, 256>(base, j0, 512, gpB);
  floatx4 acc[4][2], smax[4][2];
  ZERO_ACC42(acc);
  stage<4, 256>(gpA, LA0); bump<4>(gpA, 64);
  stage<2, 256>(gpB, LB0); bump<2>(gpB, 64);
#pragma unroll 1
  for (int f = 0; f < 4; ++f) {
#pragma unroll 1
    for (int kt = 0; kt < 8; ++kt) {
      __syncthreads();
      if (f * 8 + kt < 31) {
        if (kt == 7) { bump<4>(gpA, PLANE - 512); bump<2>(gpB, PLANE - 512); }
        stage<4, 256>(gpA, ((kt + 1) & 1) ? LA1 : LA0); bump<4>(gpA, 64);
        stage<2, 256>(gpB, ((kt + 1) & 1) ? LB1 : LB0); bump<2>(gpB, 64);
      }
      mfma_tile42((kt & 1) ? LA1 : LA0, (kt & 1) ? LB1 : LB0, acc, wm, wn, l16, quad);
    }
    if (f == 0) {
#pragma unroll
      for (int mi = 0; mi < 4; ++mi)
#pragma unroll
        for (int ni = 0; ni < 2; ++ni) smax[mi][ni] = acc[mi][ni];
    } else {
#pragma unroll
      for (int mi = 0; mi < 4; ++mi)
#pragma unroll
        for (int ni = 0; ni < 2; ++ni)
#pragma unroll
          for (int r = 0; r < 4; ++r)
            smax[mi][ni][r] = fmaxf(smax[mi][ni][r], acc[mi][ni][r]);
    }
    ZERO_ACC42(acc);
  }
  float* Sb = S + (size_t)b * 1024 * 1024;
#pragma unroll
  for (int mi = 0; mi < 4; ++mi)
#pragma unroll
    for (int ni = 0; ni < 2; ++ni)
#pragma unroll
      for (int r = 0; r < 4; ++r) {
        int gi = i0 + wm * 64 + mi * 16 + quad * 4 + r;
        int gj = j0 + wn * 32 + ni * 16 + l16;
        Sb[(size_t)gi * 1024 + gj] = smax[mi][ni][r];
      }
  if (jh >= 2 * ti + 2) {
    __syncthreads();                 // staging buffers dead
    float* tl = (float*)smem;        // [128][65] fp32
#pragma unroll
    for (int mi = 0; mi < 4; ++mi)
#pragma unroll
      for (int ni = 0; ni < 2; ++ni)
#pragma unroll
        for (int r = 0; r < 4; ++r)
          tl[(wm * 64 + mi * 16 + quad * 4 + r) * 65 + (wn * 32 + ni * 16 + l16)] =
              smax[mi][ni][r];
    __syncthreads();
#pragma unroll 1
    for (int k = 0; k < 32; ++k) {
      int flat = k * 256 + t;        // 0..8191
      int rm = flat >> 7, cm = flat & 127;
      Sb[(size_t)(j0 + rm) * 1024 + (i0 + cm)] = tl[cm * 65 + rm];
    }
  }
}

// ---- K3: allennlp masked softmax per row -> alpha fp16 ----
// 8192 blocks, XCD-pinned: b = id&7 keeps S read / alpha write L2-local.

__global__ __launch_bounds__(256) void softmax_kernel(const float* __restrict__ S,
                                                      const int* __restrict__ xmask,
                                                      _Float16* __restrict__ alpha) {
  __shared__ float red[16];
  int id = blockIdx.x;
  int b = id & 7, l = id >> 3;        // b XCD pin, l: 0..1023
  int row = b * 1024 + l;
  const float* sr = S + (size_t)row * 1024;
  const int* mr = xmask + b * 1024;
  int t = threadIdx.x, lane = t & 63, wid = t >> 6;
  int rm = mr[l];
  float v[4], mm[4];
  float vmax = 0.0f;
#pragma unroll
  for (int q = 0; q < 4; ++q) {
    int i = t + q * 256;
    int m = (rm && mr[i] && (i != l)) ? 1 : 0;
    mm[q] = (float)m;
    v[q] = m ? sr[i] : 0.0f;
    vmax = fmaxf(vmax, v[q]);
  }
  for (int off = 32; off; off >>= 1) vmax = fmaxf(vmax, __shfl_down(vmax, off));
  if (lane == 0) red[wid] = vmax;
  __syncthreads();
  if (t == 0) red[8] = fmaxf(fmaxf(red[0], red[1]), fmaxf(red[2], red[3]));
  __syncthreads();
  vmax = red[8];
  float e[4], E = 0.0f, E2 = 0.0f;
#pragma unroll
  for (int q = 0; q < 4; ++q) {
    e[q] = expf(v[q] - vmax);
    E += e[q];
    E2 += e[q] * mm[q];
  }
  for (int off = 32; off; off >>= 1) {
    E += __shfl_down(E, off);
    E2 += __shfl_down(E2, off);
  }
  if (lane == 0) { red[wid] = E; red[4 + wid] = E2; }
  __syncthreads();
  if (t == 0) {
    red[9] = red[0] + red[1] + red[2] + red[3];
    red[10] = red[4] + red[5] + red[6] + red[7];
  }
  __syncthreads();
  E = red[9]; E2 = red[10];
  float inv = 1.0f / (E2 + 1e-13f * E);
  _Float16* ar = alpha + (size_t)row * 1024;
#pragma unroll
  for (int q = 0; q < 4; ++q) {
    int i = t + q * 256;
    ar[i] = (_Float16)(e[q] * mm[q] * inv);
  }
}

// ---- K4: enc[b] = alpha[b] @ x[b]  (xT (B,H,L) as B-operand) ----
// 512 blocks x 256 thr: 64-row i-tiles x 4 n-tiles x 8 b; b = id & 7 XCD pin.

__global__ __launch_bounds__(256) void attn_kernel(const _Float16* __restrict__ alpha,
                                                   const _Float16* __restrict__ xT,
                                                   _Float16* __restrict__ enc) {
  __shared__ __align__(16) _Float16 ldsA[2][64 * 64];
  __shared__ __align__(16) _Float16 ldsB[2][128 * 64];
  int id = blockIdx.x;
  int b = id & 7;
  int r2 = id >> 3;                 // 0..63
  int i0 = (r2 >> 2) * 64;
  int n0 = (r2 & 3) * 128;
  const _Float16* A = alpha + (size_t)b * 1024 * 1024;
  const _Float16* Bm = xT + (size_t)b * 512 * 1024;
  int t = threadIdx.x, lane = t & 63, wn = t >> 6;   // wave grid 1x4
  int quad = lane >> 4, l16 = lane & 15;
  const _Float16* gpA[2]; const _Float16* gpB[4];
  init_ptrs<2, 256>(A, i0, 1024, gpA);
  init_ptrs<4, 256>(Bm, n0, 1024, gpB);
  floatx4 acc[4][2];
  ZERO_ACC42(acc);
  stage<2, 256>(gpA, ldsA[0]); bump<2>(gpA, 64);
  stage<4, 256>(gpB, ldsB[0]); bump<4>(gpB, 64);
#pragma unroll 1
  for (int kt = 0; kt < 16; ++kt) {
    __syncthreads();
    if (kt < 15) {
      stage<2, 256>(gpA, ldsA[(kt + 1) & 1]); bump<2>(gpA, 64);
      stage<4, 256>(gpB, ldsB[(kt + 1) & 1]); bump<4>(gpB, 64);
    }
    const _Float16* la = ldsA[kt & 1];
    const _Float16* lb = ldsB[kt & 1];
#pragma unroll
    for (int kf = 0; kf < 2; ++kf) {
      half8 af[4], bf[2];
#pragma unroll
      for (int i = 0; i < 4; ++i) af[i] = frag_ld(la, i * 16 + l16, kf * 4 + quad);
#pragma unroll
      for (int i = 0; i < 2; ++i) bf[i] = frag_ld(lb, wn * 32 + i * 16 + l16, kf * 4 + quad);
#pragma unroll
      for (int mi = 0; mi < 4; ++mi)
#pragma unroll
        for (int ni = 0; ni < 2; ++ni)
          acc[mi][ni] = __builtin_amdgcn_mfma_f32_16x16x32_f16(af[mi], bf[ni], acc[mi][ni], 0, 0, 0);
    }
  }
  _Float16* eb = enc + (size_t)b * 1024 * 512;
#pragma unroll
  for (int mi = 0; mi < 4; ++mi)
#pragma unroll
    for (int ni = 0; ni < 2; ++ni)
#pragma unroll
      for (int r = 0; r < 4; ++r) {
        int gr = i0 + mi * 16 + quad * 4 + r;
        int gc = n0 + wn * 32 + ni * 16 + l16;
        eb[(size_t)gr * 512 + gc] = (_Float16)acc[mi][ni][r];
      }
}

// ---- K5: gate = sigmoid([x|enc] @ W_gate + b_gate); out = gate*[x16|enc] ----
// 512 blocks x 256 thr, XCD-batch pinned. 128x128 tile, BK=32, K=1024,
// 4-deep counted-vmcnt pipeline, 64KB LDS -> 2 blocks/CU. A switches
// x16 -> enc at tile 16.

__global__ __launch_bounds__(256, 2) void gate_kernel(const _Float16* __restrict__ x16,
                                                      const _Float16* __restrict__ enc,
                                                      const _Float16* __restrict__ WgT,
                                                      const float* __restrict__ bg,
                                                      float* __restrict__ out) {
  __shared__ __align__(16) _Float16 ldsA[4][128 * 32];   // 32 KB
  __shared__ __align__(16) _Float16 ldsB[4][128 * 32];   // 32 KB
  int id = blockIdx.x;
  int xcd = id & 7, r = id >> 3;            // r: 0..63
  int i0 = (xcd * 8 + (r & 7)) * 128;       // i-tile pinned to XCD = batch
  int n0 = (r >> 3) * 128;                  // 0..7
  int t = threadIdx.x, lane = t & 63, w = t >> 6;
  int wm = w >> 1, wn = w & 1, quad = lane >> 4, l16 = lane & 15;
  int ra = wm * 64 + l16, rb = wn * 64 + l16;
  const _Float16* gpA[2]; const _Float16* gpA2[2]; const _Float16* gpB[2];
  init_ptrs32<2, 256>(x16, i0, 512, gpA);
  init_ptrs32<2, 256>(enc, i0, 512, gpA2);
  init_ptrs32<2, 256>(WgT, n0, 1024, gpB);
  floatx4 acc[4][4];
  ZERO_ACC44(acc);
  // prologue: tiles 0,1,2
  stage<2, 256>(gpA, ldsA[0]); bump<2>(gpA, 32);
  stage<2, 256>(gpB, ldsB[0]); bump<2>(gpB, 32);
  stage<2, 256>(gpA, ldsA[1]); bump<2>(gpA, 32);
  stage<2, 256>(gpB, ldsB[1]); bump<2>(gpB, 32);
  stage<2, 256>(gpA, ldsA[2]); bump<2>(gpA, 32);
  stage<2, 256>(gpB, ldsB[2]); bump<2>(gpB, 32);
#pragma unroll 1
  for (int u = 0; u < 29; ++u) {           // K=1024 -> 32 BK=32 tiles
    WAITV(8);
    __builtin_amdgcn_s_barrier();
    int v = u + 3;
    if (v < 16) { stage<2, 256>(gpA,  ldsA[v & 3]); bump<2>(gpA, 32); }
    else        { stage<2, 256>(gpA2, ldsA[v & 3]); bump<2>(gpA2, 32); }
    stage<2, 256>(gpB, ldsB[v & 3]); bump<2>(gpB, 32);
    kstep44(ldsA[u & 3], ldsB[u & 3], acc, ra, rb, quad);
  }
  WAITV(8); __builtin_amdgcn_s_barrier(); kstep44(ldsA[1], ldsB[1], acc, ra, rb, quad);
  WAITV(4); __builtin_amdgcn_s_barrier(); kstep44(ldsA[2], ldsB[2], acc, ra, rb, quad);
  WAITV(0); __builtin_amdgcn_s_barrier(); kstep44(ldsA[3], ldsB[3], acc, ra, rb, quad);
#pragma unroll
  for (int mi = 0; mi < 4; ++mi)
#pragma unroll
    for (int ni = 0; ni < 4; ++ni)
#pragma unroll
      for (int r2 = 0; r2 < 4; ++r2) {
        int gr = i0 + wm * 64 + mi * 16 + quad * 4 + r2; // 0..8191
        int gc = n0 + wn * 64 + ni * 16 + l16;           // 0..1023
        float c = acc[mi][ni][r2] + bg[gc];
        float g = 1.0f / (1.0f + expf(-c));
        float jv = (gc < 512) ? (float)x16[(size_t)gr * 512 + gc]
                              : (float)enc[(size_t)gr * 512 + (gc - 512)];
        out[(size_t)gr * 1024 + gc] = g * jv;
      }
}

// ---- launch ----

extern "C" void kernel_launch(void* const* d_in, const int* in_sizes, int n_in,
                              void* d_out, int out_size, void* d_ws, size_t ws_size,
                              hipStream_t stream) {
  const float* x  = (const float*)d_in[0];   // (8,1024,512)
  const int* xm   = (const int*)d_in[1];     // (8,1024)
  const float* Wp = (const float*)d_in[2];   // (512,2048)
  const float* bp = (const float*)d_in[3];   // (2048)
  const float* Wg = (const float*)d_in[4];   // (1024,1024)
  const float* bg = (const float*)d_in[5];   // (1024)
  float* out = (float*)d_out;

  char* ws = (char*)d_ws;
  const size_t MB = 1024 * 1024;
  _Float16* x16 = (_Float16*)(ws);            // 8 MB  (8192,512)
  _Float16* xT  = (_Float16*)(ws + 8 * MB);   // 8 MB  (8,512,1024)
  _Float16* WpT = (_Float16*)(ws + 16 * MB);  // 2 MB  (2048,512) row-permuted
  _Float16* WgT = (_Float16*)(ws + 18 * MB);  // 2 MB  (1024,1024)
  _Float16* y_t = (_Float16*)(ws + 20 * MB);  // 32 MB (8,4,1024,512)
  float*    S   = (float*)(ws + 52 * MB);     // 32 MB (8,1024,1024)  [end: 84 MB]
  // y_t is dead after score_kernel: alias alpha/enc onto it
  _Float16* alpha = (_Float16*)(ws + 20 * MB); // 16 MB (8,1024,1024)
  _Float16* enc   = (_Float16*)(ws + 36 * MB); // 8 MB  (8,1024,512)

  prep_kernel<<<6144, 256, 0, stream>>>(x, x16, xT, Wp, WpT, Wg, WgT);

  proj_kernel<<<1024, 256, 0, stream>>>(x16, WpT, bp, y_t);
  score_kernel<<<576, 256, 0, stream>>>(y_t, S);
  softmax_kernel<<<8192, 256, 0, stream>>>(S, xm, alpha);
  attn_kernel<<<512, 256, 0, stream>>>(alpha, xT, enc);
  gate_kernel<<<512, 256, 0, stream>>>(x16, enc, WgT, bg, out);
}

// Round 6
// 207.916 us; speedup vs baseline: 1.0837x; 1.0271x over previous
//
#include <hip/hip_runtime.h>

// Problem constants: B=8, L=1024, H=512, F=4
// out = gate * [x | alpha @ x],  gate = sigmoid([x|enc] @ W_gate)
// alpha = masked_softmax(max_f(Y_f Y_f^T)),  Y = relu(x @ W_proj)
//
// Round 18 = R17 with three bugs fixed (R17 failed absmax 5.9):
//  (1) gate launch was <<<512,256>>> for a 256-block x 512-thread kernel
//      (half the tile uncomputed, n0 OOB). Now <<<256,512>>>.
//  (2) gate ph1 staged B0(kt+2) into lB[buf][0] while other waves were
//      still ds_reading bf1 from it (same-phase cross-wave race). New
//      schedule: reads ph0{af0,bf0}Q00, ph1{af1}Q10, ph2{bf1}Q11+stageA,
//      ph3{}Q01+stageB0,B1+vmcnt(6). Every stage targets a slot whose
//      last read is >=1 barrier earlier; vmcnt(6) leaves only kt's own
//      6 loads outstanding -> kt+1 tiles provably retired.
//  (3) tail under-wait (both 8-phase kernels): when the last stages are
//      skipped, vmcnt(2)/(6) no longer retires the final tiles' loads
//      before first read. At kt==NK-2 switch to vmcnt(0) (all remaining
//      stages already issued; one full drain at the tail only).
// proj: 8-phase 256^2, 8 waves 2x4, 128KB LDS, 1 blk/CU, XCD-batch pinned
// (mid-loop slot ledger audited safe). score/softmax/attn/prep unchanged.

typedef _Float16 half8 __attribute__((ext_vector_type(8)));
typedef float floatx4 __attribute__((ext_vector_type(4)));

typedef const __attribute__((address_space(1))) void* gas_ptr;
typedef __attribute__((address_space(3))) void* las_ptr;

#define WAITV(n) asm volatile("s_waitcnt vmcnt(" #n ") lgkmcnt(0)" ::: "memory")

// ---- BK=64 staging machinery (all kernels) ----
// Chunk c covers row=c>>3, group kg=c&7, global col (kg^(row&7))*8; LDS dst =
// c*16 B. Row stride 128 B -> rows never alias banks; XOR keeps frags clean.

template<int NCH, int NT>
__device__ __forceinline__ void init_ptrs(const _Float16* src, int row0, int ld,
                                          const _Float16* gp[NCH]) {
  int t = threadIdx.x;
#pragma unroll
  for (int p = 0; p < NCH; ++p) {
    int c = p * NT + t;
    int row = c >> 3;
    int kg = c & 7;
    int gk = (kg ^ (row & 7)) << 3;
    gp[p] = src + (size_t)(row0 + row) * ld + gk;
  }
}

template<int NCH, int NT>
__device__ __forceinline__ void stage(const _Float16* const gp[NCH], _Float16* ldsbuf) {
  int t = threadIdx.x;
#pragma unroll
  for (int p = 0; p < NCH; ++p)
    __builtin_amdgcn_global_load_lds((gas_ptr)gp[p],
                                     (las_ptr)(ldsbuf + t * 8 + p * NT * 8), 16, 0, 0);
}

template<int NCH>
__device__ __forceinline__ void bump(const _Float16* gp[NCH], int d) {
#pragma unroll
  for (int p = 0; p < NCH; ++p) gp[p] += d;
}

__device__ __forceinline__ half8 frag_ld(const _Float16* lds, int row, int g) {
  return *(const half8*)(lds + row * 64 + ((g ^ (row & 7)) << 3));
}

// wave tile 64x32, per-lane acc 4x2 (score/attn)
__device__ __forceinline__ void mfma_tile42(const _Float16* la, const _Float16* lb,
                                            floatx4 acc[4][2], int wm, int wn,
                                            int l16, int quad) {
#pragma unroll
  for (int kf = 0; kf < 2; ++kf) {
    half8 af[4], bf[2];
#pragma unroll
    for (int i = 0; i < 4; ++i) af[i] = frag_ld(la, wm * 64 + i * 16 + l16, kf * 4 + quad);
#pragma unroll
    for (int i = 0; i < 2; ++i) bf[i] = frag_ld(lb, wn * 32 + i * 16 + l16, kf * 4 + quad);
#pragma unroll
    for (int mi = 0; mi < 4; ++mi)
#pragma unroll
      for (int ni = 0; ni < 2; ++ni)
        acc[mi][ni] = __builtin_amdgcn_mfma_f32_16x16x32_f16(af[mi], bf[ni], acc[mi][ni], 0, 0, 0);
  }
}

#define ZERO_ACC42(acc)                                 \
  _Pragma("unroll") for (int mi = 0; mi < 4; ++mi)      \
  _Pragma("unroll") for (int ni = 0; ni < 2; ++ni)      \
  _Pragma("unroll") for (int r = 0; r < 4; ++r) acc[mi][ni][r] = 0.0f;

// 4-row quadrant (proj): acc[MB..MB+3][NB..NB+1]
#define MFMA_Q4(AF, BF, MB, NB)                                                  \
  __builtin_amdgcn_s_setprio(1);                                                 \
  _Pragma("unroll") for (int kf = 0; kf < 2; ++kf)                               \
  _Pragma("unroll") for (int j = 0; j < 4; ++j)                                  \
  _Pragma("unroll") for (int jn = 0; jn < 2; ++jn)                               \
    acc[MB + j][NB + jn] = __builtin_amdgcn_mfma_f32_16x16x32_f16(               \
        AF[kf * 4 + j], BF[kf * 2 + jn], acc[MB + j][NB + jn], 0, 0, 0);         \
  __builtin_amdgcn_s_setprio(0);

// 2-row quadrant (gate): acc[MB..MB+1][NB..NB+1]
#define MFMA_Q2(AF, BF, MB, NB)                                                  \
  __builtin_amdgcn_s_setprio(1);                                                 \
  _Pragma("unroll") for (int kf = 0; kf < 2; ++kf)                               \
  _Pragma("unroll") for (int j = 0; j < 2; ++j)                                  \
  _Pragma("unroll") for (int jn = 0; jn < 2; ++jn)                               \
    acc[MB + j][NB + jn] = __builtin_amdgcn_mfma_f32_16x16x32_f16(               \
        AF[kf * 2 + j], BF[kf * 2 + jn], acc[MB + j][NB + jn], 0, 0, 0);         \
  __builtin_amdgcn_s_setprio(0);

#define PHASE_END()                      \
  __builtin_amdgcn_s_barrier();          \
  __builtin_amdgcn_sched_barrier(0)

// ---- merged pre-pass: ids [0,4096) = x_prep, [4096,6144) = w_prep ----

__global__ __launch_bounds__(256) void prep_kernel(const float* __restrict__ xin,
                                                   _Float16* __restrict__ x16,
                                                   _Float16* __restrict__ xT,
                                                   const float* __restrict__ Wp,
                                                   _Float16* __restrict__ WpT,
                                                   const float* __restrict__ Wg,
                                                   _Float16* __restrict__ WgT) {
  __shared__ float tile[32][33];
  int id = blockIdx.x;
  int tx = threadIdx.x & 31, ty = threadIdx.x >> 5;  // 32 x 8
  if (id < 4096) {
    const int R = 1024, C = 512;
    int b = id & 7, rest = id >> 3;
    int c0 = (rest & 15) * 32, r0 = (rest >> 4) * 32;
    size_t boff = (size_t)b * R * C;
    const float* in = xin + boff;
    _Float16* o16 = x16 + boff;
    _Float16* oT = xT + boff;
#pragma unroll
    for (int i = 0; i < 32; i += 8) {
      float v = in[(size_t)(r0 + ty + i) * C + c0 + tx];
      tile[ty + i][tx] = v;
      o16[(size_t)(r0 + ty + i) * C + c0 + tx] = (_Float16)v;
    }
    __syncthreads();
#pragma unroll
    for (int i = 0; i < 32; i += 8)
      oT[(size_t)(c0 + ty + i) * R + r0 + tx] = (_Float16)tile[tx][ty + i];
  } else {
    int w = id - 4096;
    int bx = w & 63, by = (w >> 6) & 15, bz = w >> 10;
    const float* in; _Float16* out; int R, C, c0, r0;
    if (bz == 0) {
      in = Wp; out = WpT; R = 512; C = 2048;
      c0 = bx * 32; r0 = by * 32;
    } else {
      in = Wg; out = WgT; R = 1024; C = 1024;
      c0 = (bx & 31) * 32; r0 = (by * 2 + (bx >> 5)) * 32;
    }
#pragma unroll
    for (int i = 0; i < 32; i += 8)
      tile[ty + i][tx] = in[(size_t)(r0 + ty + i) * C + c0 + tx];
    __syncthreads();
#pragma unroll
    for (int i = 0; i < 32; i += 8) {
      int rr = c0 + ty + i;            // original column index of `in`
      int prow = (bz == 0) ? ((rr & 3) * 512 + (rr >> 2)) : rr;
      out[(size_t)prow * R + r0 + tx] = (_Float16)tile[tx][ty + i];
    }
  }
}

// ---- K1: y = relu(x @ W_proj + b_proj) -> y_t (B,F,L,H) fp16 ----
// 8-phase 256^2: 256 blocks x 512 thr (8 waves 2x4), 1 blk/CU, 128KB LDS.
// Stream H[s]: s = 4*kt + hs, hs = {Ah0,Bh0,Ah1,Bh1}, slot (kt&1, hs>>1).
// Phase g stages H[4kt+5+g]; vmcnt(2) at ph3 (vmcnt(0) at kt=NK-2 tail).

__global__ __launch_bounds__(512) void proj_kernel(const _Float16* __restrict__ x16,
                                                   const _Float16* __restrict__ WpT,
                                                   const float* __restrict__ bp,
                                                   _Float16* __restrict__ y_t) {
  __shared__ __align__(16) _Float16 lA[2][2][128 * 64];   // [buf][half] 64 KB
  __shared__ __align__(16) _Float16 lB[2][2][128 * 64];   // 64 KB
  const int NK = 8;                         // K=512 / 64
  int id = blockIdx.x;
  int xcd = id & 7, q = id >> 3;            // q: 0..31
  int i0 = (xcd * 4 + (q & 3)) * 256;       // batch-pinned M tile
  int n0 = (q >> 2) * 256;                  // 8 N tiles
  int t = threadIdx.x, lane = t & 63, w = t >> 6;
  int wm = w >> 2, wn = w & 3;              // 2x4 waves, wave tile 128x64
  int quad = lane >> 4, l16 = lane & 15;
  int row0 = t >> 3, kg0 = t & 7;
  int gk0 = (kg0 ^ (row0 & 7)) << 3;
  int c1 = 512 + t, row1 = c1 >> 3, kg1 = c1 & 7;
  int gk1 = (kg1 ^ (row1 & 7)) << 3;
  const _Float16* Ab = x16 + (size_t)i0 * 512;
  const _Float16* Bb = WpT + (size_t)n0 * 512;

  auto stage_s = [&](int s) {
    if (s >= 4 * NK) return;
    int hs = s & 3, kt = s >> 2, buf = kt & 1;
    int o = hs & 1, hf = hs >> 1;
    const _Float16* src = (o ? Bb : Ab) + (size_t)(hf * 128) * 512 + kt * 64;
    _Float16* dst = (o ? &lB[buf][hf][0] : &lA[buf][hf][0]) + t * 8;
    __builtin_amdgcn_global_load_lds((gas_ptr)(src + (size_t)row0 * 512 + gk0),
                                     (las_ptr)dst, 16, 0, 0);
    __builtin_amdgcn_global_load_lds((gas_ptr)(src + (size_t)row1 * 512 + gk1),
                                     (las_ptr)(dst + 4096), 16, 0, 0);
  };

  floatx4 acc[8][4];
#pragma unroll
  for (int mi = 0; mi < 8; ++mi)
#pragma unroll
    for (int ni = 0; ni < 4; ++ni)
#pragma unroll
      for (int r = 0; r < 4; ++r) acc[mi][ni][r] = 0.0f;

  // prologue: H[0..4] in flight; drain so kt0 (H[0..3]) is complete
  stage_s(0); stage_s(1); stage_s(2); stage_s(3); stage_s(4);
  WAITV(2);
  PHASE_END();

  half8 af0[8], af1[8], bf0[4], bf1[4];
  int brow = (wn & 1) * 64;
#pragma unroll 1
  for (int kt = 0; kt < NK; ++kt) {
    int buf = kt & 1;
    const _Float16* Ah = &lA[buf][wm][0];
    const _Float16* Bh = &lB[buf][wn >> 1][0];
    // ph0: Q(0,0) — read af0, bf0; stage H[4kt+5] (other buf, B0)
#pragma unroll
    for (int kf = 0; kf < 2; ++kf) {
#pragma unroll
      for (int j = 0; j < 4; ++j) af0[kf * 4 + j] = frag_ld(Ah, j * 16 + l16, kf * 4 + quad);
#pragma unroll
      for (int j = 0; j < 2; ++j) bf0[kf * 2 + j] = frag_ld(Bh, brow + j * 16 + l16, kf * 4 + quad);
    }
    MFMA_Q4(af0, bf0, 0, 0);
    stage_s(4 * kt + 5);
    PHASE_END();
    // ph1: Q(0,1) — read bf1; stage H[4kt+6] (other buf, A1)
#pragma unroll
    for (int kf = 0; kf < 2; ++kf)
#pragma unroll
      for (int j = 0; j < 2; ++j) bf1[kf * 2 + j] = frag_ld(Bh, brow + 32 + j * 16 + l16, kf * 4 + quad);
    MFMA_Q4(af0, bf1, 0, 2);
    stage_s(4 * kt + 6);
    PHASE_END();
    // ph2: Q(1,1) — read af1; stage H[4kt+7] (other buf, B1)
#pragma unroll
    for (int kf = 0; kf < 2; ++kf)
#pragma unroll
      for (int j = 0; j < 4; ++j) af1[kf * 4 + j] = frag_ld(Ah, 64 + j * 16 + l16, kf * 4 + quad);
    MFMA_Q4(af1, bf1, 4, 2);
    stage_s(4 * kt + 7);
    PHASE_END();
    // ph3: Q(1,0) — no reads; stage H[4kt+8] (curr buf A0, last read ph2)
    MFMA_Q4(af1, bf0, 4, 0);
    if (kt < NK - 2) {
      stage_s(4 * kt + 8);
      WAITV(2);                 // leaves only H[4kt+8]'s 2 loads in flight
    } else {
      WAITV(0);                 // tail: no new stages -> full drain once
    }
    PHASE_END();
  }
#pragma unroll
  for (int mi = 0; mi < 8; ++mi)
#pragma unroll
    for (int ni = 0; ni < 4; ++ni)
#pragma unroll
      for (int r = 0; r < 4; ++r) {
        int gr = i0 + wm * 128 + mi * 16 + quad * 4 + r;  // 0..8191
        int gc = n0 + wn * 64 + ni * 16 + l16;            // permuted col f*512+h
        int f = gc >> 9, h = gc & 511;
        float c = fmaxf(acc[mi][ni][r] + bp[h * 4 + f], 0.0f);
        int b = gr >> 10, l = gr & 1023;
        y_t[(((size_t)(b * 4 + f)) * 1024 + l) * 512 + h] = (_Float16)c;
      }
}

// ---- K2: S[b,i,j] = max_f sum_h Y_f[i,h] Y_f[j,h]; S symmetric ----
// 576 blocks (8 b x 72 upper-tri 128x64 tiles) x 256 thr; b = id & 7 XCD pin.

__global__ __launch_bounds__(256, 3) void score_kernel(const _Float16* __restrict__ y_t,
                                                       float* __restrict__ S) {
  __shared__ __align__(16) char smem[49152];
  _Float16* LA0 = (_Float16*)smem;              // 16 KB (128x64)
  _Float16* LA1 = (_Float16*)(smem + 16384);    // 16 KB
  _Float16* LB0 = (_Float16*)(smem + 32768);    // 8 KB (64x64)
  _Float16* LB1 = (_Float16*)(smem + 40960);    // 8 KB
  int id = blockIdx.x;
  int b = id & 7;
  int tt = id >> 3;            // 0..71 upper-tri half-tile index
  int ti = 0;
  while (tt >= 16 - 2 * ti) { tt -= 16 - 2 * ti; ++ti; }
  int jh = 2 * ti + tt;        // 2*ti .. 15
  int i0 = ti * 128, j0 = jh * 64;
  int t = threadIdx.x, lane = t & 63, w = t >> 6;
  int wm = w >> 1, wn = w & 1, quad = lane >> 4, l16 = lane & 15;
  const int PLANE = 1024 * 512;
  const _Float16* base = y_t + (size_t)b * 4 * PLANE;
  const _Float16* gpA[4]; const _Float16* gpB[2];
  init_ptrs<4, 256>(base, i0, 512, gpA);
  init_ptrs<2, 256>(base, j0, 512, gpB);
  floatx4 acc[4][2], smax[4][2];
  ZERO_ACC42(acc);
  stage<4, 256>(gpA, LA0); bump<4>(gpA, 64);
  stage<2, 256>(gpB, LB0); bump<2>(gpB, 64);
#pragma unroll 1
  for (int f = 0; f < 4; ++f) {
#pragma unroll 1
    for (int kt = 0; kt < 8; ++kt) {
      __syncthreads();
      if (f * 8 + kt < 31) {
        if (kt == 7) { bump<4>(gpA, PLANE - 512); bump<2>(gpB, PLANE - 512); }
        stage<4, 256>(gpA, ((kt + 1) & 1) ? LA1 : LA0); bump<4>(gpA, 64);
        stage<2, 256>(gpB, ((kt + 1) & 1) ? LB1 : LB0); bump<2>(gpB, 64);
      }
      mfma_tile42((kt & 1) ? LA1 : LA0, (kt & 1) ? LB1 : LB0, acc, wm, wn, l16, quad);
    }
    if (f == 0) {
#pragma unroll
      for (int mi = 0; mi < 4; ++mi)
#pragma unroll
        for (int ni = 0; ni < 2; ++ni) smax[mi][ni] = acc[mi][ni];
    } else {
#pragma unroll
      for (int mi = 0; mi < 4; ++mi)
#pragma unroll
        for (int ni = 0; ni < 2; ++ni)
#pragma unroll
          for (int r = 0; r < 4; ++r)
            smax[mi][ni][r] = fmaxf(smax[mi][ni][r], acc[mi][ni][r]);
    }
    ZERO_ACC42(acc);
  }
  float* Sb = S + (size_t)b * 1024 * 1024;
#pragma unroll
  for (int mi = 0; mi < 4; ++mi)
#pragma unroll
    for (int ni = 0; ni < 2; ++ni)
#pragma unroll
      for (int r = 0; r < 4; ++r) {
        int gi = i0 + wm * 64 + mi * 16 + quad * 4 + r;
        int gj = j0 + wn * 32 + ni * 16 + l16;
        Sb[(size_t)gi * 1024 + gj] = smax[mi][ni][r];
      }
  if (jh >= 2 * ti + 2) {
    __syncthreads();                 // staging buffers dead
    float* tl = (float*)smem;        // [128][65] fp32
#pragma unroll
    for (int mi = 0; mi < 4; ++mi)
#pragma unroll
      for (int ni = 0; ni < 2; ++ni)
#pragma unroll
        for (int r = 0; r < 4; ++r)
          tl[(wm * 64 + mi * 16 + quad * 4 + r) * 65 + (wn * 32 + ni * 16 + l16)] =
              smax[mi][ni][r];
    __syncthreads();
#pragma unroll 1
    for (int k = 0; k < 32; ++k) {
      int flat = k * 256 + t;        // 0..8191
      int rm = flat >> 7, cm = flat & 127;
      Sb[(size_t)(j0 + rm) * 1024 + (i0 + cm)] = tl[cm * 65 + rm];
    }
  }
}

// ---- K3: allennlp masked softmax per row -> alpha fp16 ----
// 8192 blocks, XCD-pinned: b = id&7 keeps S read / alpha write L2-local.

__global__ __launch_bounds__(256) void softmax_kernel(const float* __restrict__ S,
                                                      const int* __restrict__ xmask,
                                                      _Float16* __restrict__ alpha) {
  __shared__ float red[16];
  int id = blockIdx.x;
  int b = id & 7, l = id >> 3;        // b XCD pin, l: 0..1023
  int row = b * 1024 + l;
  const float* sr = S + (size_t)row * 1024;
  const int* mr = xmask + b * 1024;
  int t = threadIdx.x, lane = t & 63, wid = t >> 6;
  int rm = mr[l];
  float v[4], mm[4];
  float vmax = 0.0f;
#pragma unroll
  for (int q = 0; q < 4; ++q) {
    int i = t + q * 256;
    int m = (rm && mr[i] && (i != l)) ? 1 : 0;
    mm[q] = (float)m;
    v[q] = m ? sr[i] : 0.0f;
    vmax = fmaxf(vmax, v[q]);
  }
  for (int off = 32; off; off >>= 1) vmax = fmaxf(vmax, __shfl_down(vmax, off));
  if (lane == 0) red[wid] = vmax;
  __syncthreads();
  if (t == 0) red[8] = fmaxf(fmaxf(red[0], red[1]), fmaxf(red[2], red[3]));
  __syncthreads();
  vmax = red[8];
  float e[4], E = 0.0f, E2 = 0.0f;
#pragma unroll
  for (int q = 0; q < 4; ++q) {
    e[q] = expf(v[q] - vmax);
    E += e[q];
    E2 += e[q] * mm[q];
  }
  for (int off = 32; off; off >>= 1) {
    E += __shfl_down(E, off);
    E2 += __shfl_down(E2, off);
  }
  if (lane == 0) { red[wid] = E; red[4 + wid] = E2; }
  __syncthreads();
  if (t == 0) {
    red[9] = red[0] + red[1] + red[2] + red[3];
    red[10] = red[4] + red[5] + red[6] + red[7];
  }
  __syncthreads();
  E = red[9]; E2 = red[10];
  float inv = 1.0f / (E2 + 1e-13f * E);
  _Float16* ar = alpha + (size_t)row * 1024;
#pragma unroll
  for (int q = 0; q < 4; ++q) {
    int i = t + q * 256;
    ar[i] = (_Float16)(e[q] * mm[q] * inv);
  }
}

// ---- K4: enc[b] = alpha[b] @ x[b]  (xT (B,H,L) as B-operand) ----
// 512 blocks x 256 thr: 64-row i-tiles x 4 n-tiles x 8 b; b = id & 7 XCD pin.

__global__ __launch_bounds__(256) void attn_kernel(const _Float16* __restrict__ alpha,
                                                   const _Float16* __restrict__ xT,
                                                   _Float16* __restrict__ enc) {
  __shared__ __align__(16) _Float16 ldsA[2][64 * 64];
  __shared__ __align__(16) _Float16 ldsB[2][128 * 64];
  int id = blockIdx.x;
  int b = id & 7;
  int r2 = id >> 3;                 // 0..63
  int i0 = (r2 >> 2) * 64;
  int n0 = (r2 & 3) * 128;
  const _Float16* A = alpha + (size_t)b * 1024 * 1024;
  const _Float16* Bm = xT + (size_t)b * 512 * 1024;
  int t = threadIdx.x, lane = t & 63, wn = t >> 6;   // wave grid 1x4
  int quad = lane >> 4, l16 = lane & 15;
  const _Float16* gpA[2]; const _Float16* gpB[4];
  init_ptrs<2, 256>(A, i0, 1024, gpA);
  init_ptrs<4, 256>(Bm, n0, 1024, gpB);
  floatx4 acc[4][2];
  ZERO_ACC42(acc);
  stage<2, 256>(gpA, ldsA[0]); bump<2>(gpA, 64);
  stage<4, 256>(gpB, ldsB[0]); bump<4>(gpB, 64);
#pragma unroll 1
  for (int kt = 0; kt < 16; ++kt) {
    __syncthreads();
    if (kt < 15) {
      stage<2, 256>(gpA, ldsA[(kt + 1) & 1]); bump<2>(gpA, 64);
      stage<4, 256>(gpB, ldsB[(kt + 1) & 1]); bump<4>(gpB, 64);
    }
    const _Float16* la = ldsA[kt & 1];
    const _Float16* lb = ldsB[kt & 1];
#pragma unroll
    for (int kf = 0; kf < 2; ++kf) {
      half8 af[4], bf[2];
#pragma unroll
      for (int i = 0; i < 4; ++i) af[i] = frag_ld(la, i * 16 + l16, kf * 4 + quad);
#pragma unroll
      for (int i = 0; i < 2; ++i) bf[i] = frag_ld(lb, wn * 32 + i * 16 + l16, kf * 4 + quad);
#pragma unroll
      for (int mi = 0; mi < 4; ++mi)
#pragma unroll
        for (int ni = 0; ni < 2; ++ni)
          acc[mi][ni] = __builtin_amdgcn_mfma_f32_16x16x32_f16(af[mi], bf[ni], acc[mi][ni], 0, 0, 0);
    }
  }
  _Float16* eb = enc + (size_t)b * 1024 * 512;
#pragma unroll
  for (int mi = 0; mi < 4; ++mi)
#pragma unroll
    for (int ni = 0; ni < 2; ++ni)
#pragma unroll
      for (int r = 0; r < 4; ++r) {
        int gr = i0 + mi * 16 + quad * 4 + r;
        int gc = n0 + wn * 32 + ni * 16 + l16;
        eb[(size_t)gr * 512 + gc] = (_Float16)acc[mi][ni][r];
      }
}

// ---- K5: gate = sigmoid([x|enc] @ W_gate + b_gate); out = gate*[x16|enc] ----
// 8-phase 128x256: 256 blocks x 512 thr (8 waves 2x4, wave tile 64x64),
// 96KB LDS, 1 blk/CU, XCD-batch pinned. Schedule (race-free ledger):
//   ph0 reads af0,bf0 -> Q00 | ph1 reads af1 -> Q10 (lA last read)
//   ph2 reads bf1 -> Q11, stage A(kt+2)  [lA[buf] last read ph1]
//   ph3 Q01, stage B0,B1(kt+2) [lB[buf] last read ph2], vmcnt(6)
// vmcnt(6) leaves only kt's 6 loads outstanding -> kt+1 tiles retired.
// Tail kt=NK-2: vmcnt(0). A: x16 (kt<8) then enc.

__global__ __launch_bounds__(512) void gate_kernel(const _Float16* __restrict__ x16,
                                                   const _Float16* __restrict__ enc,
                                                   const _Float16* __restrict__ WgT,
                                                   const float* __restrict__ bg,
                                                   float* __restrict__ out) {
  __shared__ __align__(16) _Float16 lA[2][128 * 64];      // 32 KB
  __shared__ __align__(16) _Float16 lB[2][2][128 * 64];   // 64 KB
  const int NK = 16;                        // K=1024 / 64
  int id = blockIdx.x;
  int xcd = id & 7, q = id >> 3;            // q: 0..31
  int i0 = (xcd * 8 + (q & 7)) * 128;       // batch-pinned M tile
  int n0 = (q >> 3) * 256;                  // 4 N tiles
  int t = threadIdx.x, lane = t & 63, w = t >> 6;
  int wm = w >> 2, wn = w & 3;              // 2x4 waves, wave tile 64x64
  int quad = lane >> 4, l16 = lane & 15;
  int row0 = t >> 3, kg0 = t & 7;
  int gk0 = (kg0 ^ (row0 & 7)) << 3;
  int c1 = 512 + t, row1 = c1 >> 3, kg1 = c1 & 7;
  int gk1 = (kg1 ^ (row1 & 7)) << 3;
  const _Float16* Ax = x16 + (size_t)i0 * 512;
  const _Float16* Ae = enc + (size_t)i0 * 512;
  const _Float16* Bb = WgT + (size_t)n0 * 1024;

  auto stageA = [&](int kt) {
    if (kt >= NK) return;
    const _Float16* src = (kt < 8 ? Ax + kt * 64 : Ae + (kt - 8) * 64);
    _Float16* dst = &lA[kt & 1][0] + t * 8;
    __builtin_amdgcn_global_load_lds((gas_ptr)(src + (size_t)row0 * 512 + gk0),
                                     (las_ptr)dst, 16, 0, 0);
    __builtin_amdgcn_global_load_lds((gas_ptr)(src + (size_t)row1 * 512 + gk1),
                                     (las_ptr)(dst + 4096), 16, 0, 0);
  };
  auto stageB = [&](int kt, int hf) {
    if (kt >= NK) return;
    const _Float16* src = Bb + (size_t)(hf * 128) * 1024 + kt * 64;
    _Float16* dst = &lB[kt & 1][hf][0] + t * 8;
    __builtin_amdgcn_global_load_lds((gas_ptr)(src + (size_t)row0 * 1024 + gk0),
                                     (las_ptr)dst, 16, 0, 0);
    __builtin_amdgcn_global_load_lds((gas_ptr)(src + (size_t)row1 * 1024 + gk1),
                                     (las_ptr)(dst + 4096), 16, 0, 0);
  };

  floatx4 acc[4][4];
#pragma unroll
  for (int mi = 0; mi < 4; ++mi)
#pragma unroll
    for (int ni = 0; ni < 4; ++ni)
#pragma unroll
      for (int r = 0; r < 4; ++r) acc[mi][ni][r] = 0.0f;

  // prologue: kt0 {A,B0,B1} + kt1 {A,B0,B1}; vmcnt(6) -> kt0 complete
  stageA(0); stageB(0, 0); stageB(0, 1);
  stageA(1); stageB(1, 0); stageB(1, 1);
  WAITV(6);
  PHASE_END();

  half8 af0[4], af1[4], bf0[4], bf1[4];
  int arow = wm * 64, brow = (wn & 1) * 64;
#pragma unroll 1
  for (int kt = 0; kt < NK; ++kt) {
    int buf = kt & 1;
    const _Float16* Ah = &lA[buf][0];
    const _Float16* Bh = &lB[buf][wn >> 1][0];
    // ph0: Q(0,0) — read af0, bf0
#pragma unroll
    for (int kf = 0; kf < 2; ++kf) {
#pragma unroll
      for (int j = 0; j < 2; ++j) {
        af0[kf * 2 + j] = frag_ld(Ah, arow + j * 16 + l16, kf * 4 + quad);
        bf0[kf * 2 + j] = frag_ld(Bh, brow + j * 16 + l16, kf * 4 + quad);
      }
    }
    MFMA_Q2(af0, bf0, 0, 0);
    PHASE_END();
    // ph1: Q(1,0) — read af1 (last lA[buf] read)
#pragma unroll
    for (int kf = 0; kf < 2; ++kf)
#pragma unroll
      for (int j = 0; j < 2; ++j)
        af1[kf * 2 + j] = frag_ld(Ah, arow + 32 + j * 16 + l16, kf * 4 + quad);
    MFMA_Q2(af1, bf0, 2, 0);
    PHASE_END();
    // ph2: Q(1,1) — read bf1 (last lB[buf] read); stage A(kt+2)
#pragma unroll
    for (int kf = 0; kf < 2; ++kf)
#pragma unroll
      for (int j = 0; j < 2; ++j)
        bf1[kf * 2 + j] = frag_ld(Bh, brow + 32 + j * 16 + l16, kf * 4 + quad);
    MFMA_Q2(af1, bf1, 2, 2);
    stageA(kt + 2);
    PHASE_END();
    // ph3: Q(0,1) — no reads; stage B0,B1(kt+2); checkpoint
    MFMA_Q2(af0, bf1, 0, 2);
    if (kt < NK - 2) {
      stageB(kt + 2, 0);
      stageB(kt + 2, 1);
      WAITV(6);                 // leaves only kt's 6 loads in flight
    } else {
      WAITV(0);                 // tail: full drain once
    }
    PHASE_END();
  }
#pragma unroll
  for (int mi = 0; mi < 4; ++mi)
#pragma unroll
    for (int ni = 0; ni < 4; ++ni)
#pragma unroll
      for (int r = 0; r < 4; ++r) {
        int gr = i0 + wm * 64 + mi * 16 + quad * 4 + r;  // 0..8191
        int gc = n0 + wn * 64 + ni * 16 + l16;           // 0..1023
        float c = acc[mi][ni][r] + bg[gc];
        float g = 1.0f / (1.0f + expf(-c));
        float jv = (gc < 512) ? (float)x16[(size_t)gr * 512 + gc]
                              : (float)enc[(size_t)gr * 512 + (gc - 512)];
        out[(size_t)gr * 1024 + gc] = g * jv;
      }
}

// ---- launch ----

extern "C" void kernel_launch(void* const* d_in, const int* in_sizes, int n_in,
                              void* d_out, int out_size, void* d_ws, size_t ws_size,
                              hipStream_t stream) {
  const float* x  = (const float*)d_in[0];   // (8,1024,512)
  const int* xm   = (const int*)d_in[1];     // (8,1024)
  const float* Wp = (const float*)d_in[2];   // (512,2048)
  const float* bp = (const float*)d_in[3];   // (2048)
  const float* Wg = (const float*)d_in[4];   // (1024,1024)
  const float* bg = (const float*)d_in[5];   // (1024)
  float* out = (float*)d_out;

  char* ws = (char*)d_ws;
  const size_t MB = 1024 * 1024;
  _Float16* x16 = (_Float16*)(ws);            // 8 MB  (8192,512)
  _Float16* xT  = (_Float16*)(ws + 8 * MB);   // 8 MB  (8,512,1024)
  _Float16* WpT = (_Float16*)(ws + 16 * MB);  // 2 MB  (2048,512) row-permuted
  _Float16* WgT = (_Float16*)(ws + 18 * MB);  // 2 MB  (1024,1024)
  _Float16* y_t = (_Float16*)(ws + 20 * MB);  // 32 MB (8,4,1024,512)
  float*    S   = (float*)(ws + 52 * MB);     // 32 MB (8,1024,1024)  [end: 84 MB]
  // y_t is dead after score_kernel: alias alpha/enc onto it
  _Float16* alpha = (_Float16*)(ws + 20 * MB); // 16 MB (8,1024,1024)
  _Float16* enc   = (_Float16*)(ws + 36 * MB); // 8 MB  (8,1024,512)

  prep_kernel<<<6144, 256, 0, stream>>>(x, x16, xT, Wp, WpT, Wg, WgT);

  proj_kernel<<<256, 512, 0, stream>>>(x16, WpT, bp, y_t);
  score_kernel<<<576, 256, 0, stream>>>(y_t, S);
  softmax_kernel<<<8192, 256, 0, stream>>>(S, xm, alpha);
  attn_kernel<<<512, 256, 0, stream>>>(alpha, xT, enc);
  gate_kernel<<<256, 512, 0, stream>>>(x16, enc, WgT, bg, out);
}

// Round 7
// 198.894 us; speedup vs baseline: 1.1329x; 1.0454x over previous
//
#include <hip/hip_runtime.h>

// Problem constants: B=8, L=1024, H=512, F=4
// out = gate * [x | alpha @ x],  gate = sigmoid([x|enc] @ W_gate)
// alpha = masked_softmax(max_f(Y_f Y_f^T)),  Y = relu(x @ W_proj)
//
// Round 19: REVERT to the measured-best R13 structure (200.2us) after four
// deep-pipeline variants (R15 4-deep 512thr, R16 4-deep 2blk, R17/R18
// 8-phase) all measured slower (225/213/fail/208). At these shapes
// (K=512/1024, ~17GF/GEMM) inter-block wave overlap at 2 blocks/CU already
// hides staging latency; 1-blk/CU lockstep + extra barriers eat the gains.
// Kept from the experiments: single merged prep dispatch (7->6 launches).
// proj/gate: 2-phase dbuf BK=64, 128x128 tiles, 2D grids. score: 576
// upper-tri 128x64 half-tiles, 3 blk/CU. softmax/attn: R13 forms.

typedef _Float16 half8 __attribute__((ext_vector_type(8)));
typedef float floatx4 __attribute__((ext_vector_type(4)));

typedef const __attribute__((address_space(1))) void* gas_ptr;
typedef __attribute__((address_space(3))) void* las_ptr;

// ---- staging machinery: BK=64 rows (64 fp16/row), XOR-swizzle by row&7 ----
// Chunk c covers row=c>>3, group kg=c&7, global col (kg^(row&7))*8; LDS dst =
// c*16 B (wave-uniform base + lane*16 contract of global_load_lds). Row
// stride 128 B = 32 banks -> rows never alias; swizzle makes frag reads clean.

template<int NCH, int NT>
__device__ __forceinline__ void init_ptrs(const _Float16* src, int row0, int ld,
                                          const _Float16* gp[NCH]) {
  int t = threadIdx.x;
#pragma unroll
  for (int p = 0; p < NCH; ++p) {
    int c = p * NT + t;
    int row = c >> 3;
    int kg = c & 7;
    int gk = (kg ^ (row & 7)) << 3;
    gp[p] = src + (size_t)(row0 + row) * ld + gk;
  }
}

template<int NCH, int NT>
__device__ __forceinline__ void stage(const _Float16* const gp[NCH], _Float16* ldsbuf) {
  int t = threadIdx.x;
#pragma unroll
  for (int p = 0; p < NCH; ++p)
    __builtin_amdgcn_global_load_lds((gas_ptr)gp[p],
                                     (las_ptr)(ldsbuf + t * 8 + p * NT * 8), 16, 0, 0);
}

template<int NCH>
__device__ __forceinline__ void bump(const _Float16* gp[NCH], int d) {
#pragma unroll
  for (int p = 0; p < NCH; ++p) gp[p] += d;
}

__device__ __forceinline__ half8 frag_ld(const _Float16* lds, int row, int g) {
  return *(const half8*)(lds + row * 64 + ((g ^ (row & 7)) << 3));
}

// 4-wave (2x2) block: wave tile 64x64, per-lane acc 4x4
__device__ __forceinline__ void mfma_tile44(const _Float16* lds_a, const _Float16* lds_b,
                                            floatx4 acc[4][4], int wm, int wn,
                                            int l16, int quad) {
#pragma unroll
  for (int kf = 0; kf < 2; ++kf) {
    half8 af[4], bf[4];
#pragma unroll
    for (int i = 0; i < 4; ++i) af[i] = frag_ld(lds_a, wm * 64 + i * 16 + l16, kf * 4 + quad);
#pragma unroll
    for (int i = 0; i < 4; ++i) bf[i] = frag_ld(lds_b, wn * 64 + i * 16 + l16, kf * 4 + quad);
#pragma unroll
    for (int mi = 0; mi < 4; ++mi)
#pragma unroll
      for (int ni = 0; ni < 4; ++ni)
        acc[mi][ni] = __builtin_amdgcn_mfma_f32_16x16x32_f16(af[mi], bf[ni], acc[mi][ni], 0, 0, 0);
  }
}

#define ZERO_ACC44(acc)                                 \
  _Pragma("unroll") for (int mi = 0; mi < 4; ++mi)      \
  _Pragma("unroll") for (int ni = 0; ni < 4; ++ni)      \
  _Pragma("unroll") for (int r = 0; r < 4; ++r) acc[mi][ni][r] = 0.0f;

// wave tile 64x32, per-lane acc 4x2 (score/attn)
__device__ __forceinline__ void mfma_tile42(const _Float16* la, const _Float16* lb,
                                            floatx4 acc[4][2], int wm, int wn,
                                            int l16, int quad) {
#pragma unroll
  for (int kf = 0; kf < 2; ++kf) {
    half8 af[4], bf[2];
#pragma unroll
    for (int i = 0; i < 4; ++i) af[i] = frag_ld(la, wm * 64 + i * 16 + l16, kf * 4 + quad);
#pragma unroll
    for (int i = 0; i < 2; ++i) bf[i] = frag_ld(lb, wn * 32 + i * 16 + l16, kf * 4 + quad);
#pragma unroll
    for (int mi = 0; mi < 4; ++mi)
#pragma unroll
      for (int ni = 0; ni < 2; ++ni)
        acc[mi][ni] = __builtin_amdgcn_mfma_f32_16x16x32_f16(af[mi], bf[ni], acc[mi][ni], 0, 0, 0);
  }
}

#define ZERO_ACC42(acc)                                 \
  _Pragma("unroll") for (int mi = 0; mi < 4; ++mi)      \
  _Pragma("unroll") for (int ni = 0; ni < 2; ++ni)      \
  _Pragma("unroll") for (int r = 0; r < 4; ++r) acc[mi][ni][r] = 0.0f;

// ---- merged pre-pass: ids [0,4096) = x_prep, [4096,6144) = w_prep ----

__global__ __launch_bounds__(256) void prep_kernel(const float* __restrict__ xin,
                                                   _Float16* __restrict__ x16,
                                                   _Float16* __restrict__ xT,
                                                   const float* __restrict__ Wp,
                                                   _Float16* __restrict__ WpT,
                                                   const float* __restrict__ Wg,
                                                   _Float16* __restrict__ WgT) {
  __shared__ float tile[32][33];
  int id = blockIdx.x;
  int tx = threadIdx.x & 31, ty = threadIdx.x >> 5;  // 32 x 8
  if (id < 4096) {
    const int R = 1024, C = 512;
    int b = id & 7, rest = id >> 3;
    int c0 = (rest & 15) * 32, r0 = (rest >> 4) * 32;
    size_t boff = (size_t)b * R * C;
    const float* in = xin + boff;
    _Float16* o16 = x16 + boff;
    _Float16* oT = xT + boff;
#pragma unroll
    for (int i = 0; i < 32; i += 8) {
      float v = in[(size_t)(r0 + ty + i) * C + c0 + tx];
      tile[ty + i][tx] = v;
      o16[(size_t)(r0 + ty + i) * C + c0 + tx] = (_Float16)v;
    }
    __syncthreads();
#pragma unroll
    for (int i = 0; i < 32; i += 8)
      oT[(size_t)(c0 + ty + i) * R + r0 + tx] = (_Float16)tile[tx][ty + i];
  } else {
    // z=0: Wp (512,2048) -> WpT' (2048,512) row-permuted (col k=h*4+f ->
    // row f*512+h, so proj's output col n = f*512+h). z=1: Wg -> WgT.
    int w = id - 4096;
    int bx = w & 63, by = (w >> 6) & 15, bz = w >> 10;
    const float* in; _Float16* out; int R, C, c0, r0;
    if (bz == 0) {
      in = Wp; out = WpT; R = 512; C = 2048;
      c0 = bx * 32; r0 = by * 32;
    } else {
      in = Wg; out = WgT; R = 1024; C = 1024;
      c0 = (bx & 31) * 32; r0 = (by * 2 + (bx >> 5)) * 32;
    }
#pragma unroll
    for (int i = 0; i < 32; i += 8)
      tile[ty + i][tx] = in[(size_t)(r0 + ty + i) * C + c0 + tx];
    __syncthreads();
#pragma unroll
    for (int i = 0; i < 32; i += 8) {
      int rr = c0 + ty + i;            // original column index of `in`
      int prow = (bz == 0) ? ((rr & 3) * 512 + (rr >> 2)) : rr;
      out[(size_t)prow * R + r0 + tx] = (_Float16)tile[tx][ty + i];
    }
  }
}

// ---- K1: y = relu(x @ W_proj + b_proj) -> y_t (B,F,L,H) fp16 ----
// 256 thr, 2x2 waves, 128x128 tile, dbuf BK=64, grid (64,16), 2 blk/CU.
// Output col n = f*512+h (WpT pre-permuted) -> 32B-contiguous quad stores.

__global__ __launch_bounds__(256) void proj_kernel(const _Float16* __restrict__ x16,
                                                   const _Float16* __restrict__ WpT,
                                                   const float* __restrict__ bp,
                                                   _Float16* __restrict__ y_t) {
  __shared__ __align__(16) _Float16 ldsA[2][128 * 64];
  __shared__ __align__(16) _Float16 ldsB[2][128 * 64];
  int i0 = blockIdx.x * 128, n0 = blockIdx.y * 128;
  int t = threadIdx.x, lane = t & 63, w = t >> 6;
  int wm = w >> 1, wn = w & 1, quad = lane >> 4, l16 = lane & 15;
  const _Float16* gpA[4]; const _Float16* gpB[4];
  init_ptrs<4, 256>(x16, i0, 512, gpA);
  init_ptrs<4, 256>(WpT, n0, 512, gpB);
  floatx4 acc[4][4];
  ZERO_ACC44(acc);
  stage<4, 256>(gpA, ldsA[0]); bump<4>(gpA, 64);
  stage<4, 256>(gpB, ldsB[0]); bump<4>(gpB, 64);
#pragma unroll 1
  for (int kt = 0; kt < 8; ++kt) {
    __syncthreads();
    if (kt < 7) {
      stage<4, 256>(gpA, ldsA[(kt + 1) & 1]); bump<4>(gpA, 64);
      stage<4, 256>(gpB, ldsB[(kt + 1) & 1]); bump<4>(gpB, 64);
    }
    mfma_tile44(ldsA[kt & 1], ldsB[kt & 1], acc, wm, wn, l16, quad);
  }
#pragma unroll
  for (int mi = 0; mi < 4; ++mi)
#pragma unroll
    for (int ni = 0; ni < 4; ++ni)
#pragma unroll
      for (int r = 0; r < 4; ++r) {
        int gr = i0 + wm * 64 + mi * 16 + quad * 4 + r;   // 0..8191
        int gc = n0 + wn * 64 + ni * 16 + l16;            // permuted col f*512+h
        int f = gc >> 9, h = gc & 511;
        float c = fmaxf(acc[mi][ni][r] + bp[h * 4 + f], 0.0f);
        int b = gr >> 10, l = gr & 1023;
        y_t[(((size_t)(b * 4 + f)) * 1024 + l) * 512 + h] = (_Float16)c;
      }
}

// ---- K2: S[b,i,j] = max_f sum_h Y_f[i,h] Y_f[j,h]; S symmetric ----
// 576 blocks (8 b x 72 upper-tri 128x64 tiles) x 256 thr; b = id & 7 XCD pin.
// 48KB LDS -> 3 blocks/CU. Diagonal covered by jh=2ti/2ti+1 direct;
// jh>=2ti+2 mirrored via [128][65] fp32 LDS transpose (conflict-free).

__global__ __launch_bounds__(256, 3) void score_kernel(const _Float16* __restrict__ y_t,
                                                       float* __restrict__ S) {
  __shared__ __align__(16) char smem[49152];
  _Float16* LA0 = (_Float16*)smem;              // 16 KB (128x64)
  _Float16* LA1 = (_Float16*)(smem + 16384);    // 16 KB
  _Float16* LB0 = (_Float16*)(smem + 32768);    // 8 KB (64x64)
  _Float16* LB1 = (_Float16*)(smem + 40960);    // 8 KB
  int id = blockIdx.x;
  int b = id & 7;
  int tt = id >> 3;            // 0..71 upper-tri half-tile index
  int ti = 0;
  while (tt >= 16 - 2 * ti) { tt -= 16 - 2 * ti; ++ti; }
  int jh = 2 * ti + tt;        // 2*ti .. 15
  int i0 = ti * 128, j0 = jh * 64;
  int t = threadIdx.x, lane = t & 63, w = t >> 6;
  int wm = w >> 1, wn = w & 1, quad = lane >> 4, l16 = lane & 15;
  const int PLANE = 1024 * 512;
  const _Float16* base = y_t + (size_t)b * 4 * PLANE;
  const _Float16* gpA[4]; const _Float16* gpB[2];
  init_ptrs<4, 256>(base, i0, 512, gpA);
  init_ptrs<2, 256>(base, j0, 512, gpB);
  floatx4 acc[4][2], smax[4][2];
  ZERO_ACC42(acc);
  stage<4, 256>(gpA, LA0); bump<4>(gpA, 64);
  stage<2, 256>(gpB, LB0); bump<2>(gpB, 64);
#pragma unroll 1
  for (int f = 0; f < 4; ++f) {
#pragma unroll 1
    for (int kt = 0; kt < 8; ++kt) {
      __syncthreads();
      if (f * 8 + kt < 31) {
        if (kt == 7) { bump<4>(gpA, PLANE - 512); bump<2>(gpB, PLANE - 512); }
        stage<4, 256>(gpA, ((kt + 1) & 1) ? LA1 : LA0); bump<4>(gpA, 64);
        stage<2, 256>(gpB, ((kt + 1) & 1) ? LB1 : LB0); bump<2>(gpB, 64);
      }
      mfma_tile42((kt & 1) ? LA1 : LA0, (kt & 1) ? LB1 : LB0, acc, wm, wn, l16, quad);
    }
    if (f == 0) {
#pragma unroll
      for (int mi = 0; mi < 4; ++mi)
#pragma unroll
        for (int ni = 0; ni < 2; ++ni) smax[mi][ni] = acc[mi][ni];
    } else {
#pragma unroll
      for (int mi = 0; mi < 4; ++mi)
#pragma unroll
        for (int ni = 0; ni < 2; ++ni)
#pragma unroll
          for (int r = 0; r < 4; ++r)
            smax[mi][ni][r] = fmaxf(smax[mi][ni][r], acc[mi][ni][r]);
    }
    ZERO_ACC42(acc);
  }
  float* Sb = S + (size_t)b * 1024 * 1024;
#pragma unroll
  for (int mi = 0; mi < 4; ++mi)
#pragma unroll
    for (int ni = 0; ni < 2; ++ni)
#pragma unroll
      for (int r = 0; r < 4; ++r) {
        int gi = i0 + wm * 64 + mi * 16 + quad * 4 + r;
        int gj = j0 + wn * 32 + ni * 16 + l16;
        Sb[(size_t)gi * 1024 + gj] = smax[mi][ni][r];
      }
  if (jh >= 2 * ti + 2) {
    __syncthreads();                 // staging buffers dead
    float* tl = (float*)smem;        // [128][65] fp32
#pragma unroll
    for (int mi = 0; mi < 4; ++mi)
#pragma unroll
      for (int ni = 0; ni < 2; ++ni)
#pragma unroll
        for (int r = 0; r < 4; ++r)
          tl[(wm * 64 + mi * 16 + quad * 4 + r) * 65 + (wn * 32 + ni * 16 + l16)] =
              smax[mi][ni][r];
    __syncthreads();
#pragma unroll 1
    for (int k = 0; k < 32; ++k) {
      int flat = k * 256 + t;        // 0..8191
      int rm = flat >> 7, cm = flat & 127;   // rm: mirror row 0..63, cm: col 0..127
      Sb[(size_t)(j0 + rm) * 1024 + (i0 + cm)] = tl[cm * 65 + rm];
    }
  }
}

// ---- K3: allennlp masked softmax per row -> alpha fp16 ----

__global__ __launch_bounds__(256) void softmax_kernel(const float* __restrict__ S,
                                                      const int* __restrict__ xmask,
                                                      _Float16* __restrict__ alpha) {
  __shared__ float red[16];
  int row = blockIdx.x;               // 0..8191
  int b = row >> 10, l = row & 1023;
  const float* sr = S + (size_t)row * 1024;
  const int* mr = xmask + b * 1024;
  int t = threadIdx.x, lane = t & 63, wid = t >> 6;
  int rm = mr[l];
  float v[4], mm[4];
  float vmax = 0.0f;
#pragma unroll
  for (int q = 0; q < 4; ++q) {
    int i = t + q * 256;
    int m = (rm && mr[i] && (i != l)) ? 1 : 0;
    mm[q] = (float)m;
    v[q] = m ? sr[i] : 0.0f;
    vmax = fmaxf(vmax, v[q]);
  }
  for (int off = 32; off; off >>= 1) vmax = fmaxf(vmax, __shfl_down(vmax, off));
  if (lane == 0) red[wid] = vmax;
  __syncthreads();
  if (t == 0) red[8] = fmaxf(fmaxf(red[0], red[1]), fmaxf(red[2], red[3]));
  __syncthreads();
  vmax = red[8];
  float e[4], E = 0.0f, E2 = 0.0f;
#pragma unroll
  for (int q = 0; q < 4; ++q) {
    e[q] = expf(v[q] - vmax);
    E += e[q];
    E2 += e[q] * mm[q];
  }
  for (int off = 32; off; off >>= 1) {
    E += __shfl_down(E, off);
    E2 += __shfl_down(E2, off);
  }
  if (lane == 0) { red[wid] = E; red[4 + wid] = E2; }
  __syncthreads();
  if (t == 0) {
    red[9] = red[0] + red[1] + red[2] + red[3];
    red[10] = red[4] + red[5] + red[6] + red[7];
  }
  __syncthreads();
  E = red[9]; E2 = red[10];
  float inv = 1.0f / (E2 + 1e-13f * E);
  _Float16* ar = alpha + (size_t)row * 1024;
#pragma unroll
  for (int q = 0; q < 4; ++q) {
    int i = t + q * 256;
    ar[i] = (_Float16)(e[q] * mm[q] * inv);
  }
}

// ---- K4: enc[b] = alpha[b] @ x[b]  (xT (B,H,L) as B-operand) ----
// 512 blocks x 256 thr: 64-row i-tiles x 4 n-tiles x 8 b; b = id & 7 XCD pin.

__global__ __launch_bounds__(256) void attn_kernel(const _Float16* __restrict__ alpha,
                                                   const _Float16* __restrict__ xT,
                                                   _Float16* __restrict__ enc) {
  __shared__ __align__(16) _Float16 ldsA[2][64 * 64];
  __shared__ __align__(16) _Float16 ldsB[2][128 * 64];
  int id = blockIdx.x;
  int b = id & 7;
  int r2 = id >> 3;                 // 0..63
  int i0 = (r2 >> 2) * 64;
  int n0 = (r2 & 3) * 128;
  const _Float16* A = alpha + (size_t)b * 1024 * 1024;
  const _Float16* Bm = xT + (size_t)b * 512 * 1024;
  int t = threadIdx.x, lane = t & 63, wn = t >> 6;   // wave grid 1x4
  int quad = lane >> 4, l16 = lane & 15;
  const _Float16* gpA[2]; const _Float16* gpB[4];
  init_ptrs<2, 256>(A, i0, 1024, gpA);
  init_ptrs<4, 256>(Bm, n0, 1024, gpB);
  floatx4 acc[4][2];
  ZERO_ACC42(acc);
  stage<2, 256>(gpA, ldsA[0]); bump<2>(gpA, 64);
  stage<4, 256>(gpB, ldsB[0]); bump<4>(gpB, 64);
#pragma unroll 1
  for (int kt = 0; kt < 16; ++kt) {
    __syncthreads();
    if (kt < 15) {
      stage<2, 256>(gpA, ldsA[(kt + 1) & 1]); bump<2>(gpA, 64);
      stage<4, 256>(gpB, ldsB[(kt + 1) & 1]); bump<4>(gpB, 64);
    }
    const _Float16* la = ldsA[kt & 1];
    const _Float16* lb = ldsB[kt & 1];
#pragma unroll
    for (int kf = 0; kf < 2; ++kf) {
      half8 af[4], bf[2];
#pragma unroll
      for (int i = 0; i < 4; ++i) af[i] = frag_ld(la, i * 16 + l16, kf * 4 + quad);
#pragma unroll
      for (int i = 0; i < 2; ++i) bf[i] = frag_ld(lb, wn * 32 + i * 16 + l16, kf * 4 + quad);
#pragma unroll
      for (int mi = 0; mi < 4; ++mi)
#pragma unroll
        for (int ni = 0; ni < 2; ++ni)
          acc[mi][ni] = __builtin_amdgcn_mfma_f32_16x16x32_f16(af[mi], bf[ni], acc[mi][ni], 0, 0, 0);
    }
  }
  _Float16* eb = enc + (size_t)b * 1024 * 512;
#pragma unroll
  for (int mi = 0; mi < 4; ++mi)
#pragma unroll
    for (int ni = 0; ni < 2; ++ni)
#pragma unroll
      for (int r = 0; r < 4; ++r) {
        int gr = i0 + mi * 16 + quad * 4 + r;
        int gc = n0 + wn * 32 + ni * 16 + l16;
        eb[(size_t)gr * 512 + gc] = (_Float16)acc[mi][ni][r];
      }
}

// ---- K5: gate = sigmoid([x|enc] @ W_gate + b_gate); out = gate*[x16|enc] ----
// 256 thr, 2x2 waves, dbuf BK=64, grid (64,8), 2 blk/CU.

__global__ __launch_bounds__(256) void gate_kernel(const _Float16* __restrict__ x16,
                                                   const _Float16* __restrict__ enc,
                                                   const _Float16* __restrict__ WgT,
                                                   const float* __restrict__ bg,
                                                   float* __restrict__ out) {
  __shared__ __align__(16) _Float16 ldsA[2][128 * 64];
  __shared__ __align__(16) _Float16 ldsB[2][128 * 64];
  int i0 = blockIdx.x * 128, n0 = blockIdx.y * 128;
  int t = threadIdx.x, lane = t & 63, w = t >> 6;
  int wm = w >> 1, wn = w & 1, quad = lane >> 4, l16 = lane & 15;
  const _Float16* gpA[4]; const _Float16* gpA2[4]; const _Float16* gpB[4];
  init_ptrs<4, 256>(x16, i0, 512, gpA);
  init_ptrs<4, 256>(enc, i0, 512, gpA2);
  init_ptrs<4, 256>(WgT, n0, 1024, gpB);
  floatx4 acc[4][4];
  ZERO_ACC44(acc);
  stage<4, 256>(gpA, ldsA[0]); bump<4>(gpA, 64);
  stage<4, 256>(gpB, ldsB[0]); bump<4>(gpB, 64);
#pragma unroll 1
  for (int kt = 0; kt < 16; ++kt) {
    __syncthreads();
    if (kt < 15) {
      if (kt < 7) { stage<4, 256>(gpA,  ldsA[(kt + 1) & 1]); bump<4>(gpA, 64); }
      else        { stage<4, 256>(gpA2, ldsA[(kt + 1) & 1]); bump<4>(gpA2, 64); }
      stage<4, 256>(gpB, ldsB[(kt + 1) & 1]); bump<4>(gpB, 64);
    }
    mfma_tile44(ldsA[kt & 1], ldsB[kt & 1], acc, wm, wn, l16, quad);
  }
#pragma unroll
  for (int mi = 0; mi < 4; ++mi)
#pragma unroll
    for (int ni = 0; ni < 4; ++ni)
#pragma unroll
      for (int r = 0; r < 4; ++r) {
        int gr = i0 + wm * 64 + mi * 16 + quad * 4 + r;  // 0..8191
        int gc = n0 + wn * 64 + ni * 16 + l16;           // 0..1023
        float c = acc[mi][ni][r] + bg[gc];
        float g = 1.0f / (1.0f + expf(-c));
        float jv = (gc < 512) ? (float)x16[(size_t)gr * 512 + gc]
                              : (float)enc[(size_t)gr * 512 + (gc - 512)];
        out[(size_t)gr * 1024 + gc] = g * jv;
      }
}

// ---- launch ----

extern "C" void kernel_launch(void* const* d_in, const int* in_sizes, int n_in,
                              void* d_out, int out_size, void* d_ws, size_t ws_size,
                              hipStream_t stream) {
  const float* x  = (const float*)d_in[0];   // (8,1024,512)
  const int* xm   = (const int*)d_in[1];     // (8,1024)
  const float* Wp = (const float*)d_in[2];   // (512,2048)
  const float* bp = (const float*)d_in[3];   // (2048)
  const float* Wg = (const float*)d_in[4];   // (1024,1024)
  const float* bg = (const float*)d_in[5];   // (1024)
  float* out = (float*)d_out;

  char* ws = (char*)d_ws;
  const size_t MB = 1024 * 1024;
  _Float16* x16 = (_Float16*)(ws);            // 8 MB  (8192,512)
  _Float16* xT  = (_Float16*)(ws + 8 * MB);   // 8 MB  (8,512,1024)
  _Float16* WpT = (_Float16*)(ws + 16 * MB);  // 2 MB  (2048,512) row-permuted
  _Float16* WgT = (_Float16*)(ws + 18 * MB);  // 2 MB  (1024,1024)
  _Float16* y_t = (_Float16*)(ws + 20 * MB);  // 32 MB (8,4,1024,512)
  float*    S   = (float*)(ws + 52 * MB);     // 32 MB (8,1024,1024)  [end: 84 MB]
  // y_t is dead after score_kernel: alias alpha/enc onto it
  _Float16* alpha = (_Float16*)(ws + 20 * MB); // 16 MB (8,1024,1024)
  _Float16* enc   = (_Float16*)(ws + 36 * MB); // 8 MB  (8,1024,512)

  prep_kernel<<<6144, 256, 0, stream>>>(x, x16, xT, Wp, WpT, Wg, WgT);

  proj_kernel<<<dim3(64, 16), 256, 0, stream>>>(x16, WpT, bp, y_t);
  score_kernel<<<576, 256, 0, stream>>>(y_t, S);
  softmax_kernel<<<8192, 256, 0, stream>>>(S, xm, alpha);
  attn_kernel<<<512, 256, 0, stream>>>(alpha, xT, enc);
  gate_kernel<<<dim3(64, 8), 256, 0, stream>>>(x16, enc, WgT, bg, out);
}